// Round 6
// baseline (440.693 us; speedup 1.0000x reference)
//
#include <hip/hip_runtime.h>

// TransformerBlock: B=2, S=2048, D=1024, H=16, dh=64, FFN=4096.
// Round 6: chunked split-K attention — equal-length dual chains (lockstep
// ILP=2), 5120 balanced waves, longest-first dispatch, chunk partials+combine.

typedef __attribute__((ext_vector_type(8))) short s16x8;
typedef __attribute__((ext_vector_type(4))) float f32x4;
typedef unsigned short u16;
typedef unsigned int u32;

#define DEV static __device__ __forceinline__
#define MFMA16 __builtin_amdgcn_mfma_f32_16x16x32_bf16
#define GLOAD_LDS16(gp, lp)                                         \
  __builtin_amdgcn_global_load_lds(                                 \
      (const __attribute__((address_space(1))) void*)(gp),          \
      (__attribute__((address_space(3))) void*)(lp), 16, 0, 0)

DEV u16 f2bf(float f) {
  union { float f; unsigned u; } c; c.f = f;
  unsigned u = c.u;
  u += 0x7fff + ((u >> 16) & 1);   // RNE
  return (u16)(u >> 16);
}

DEV float bf2f(u16 v) {
  union { u32 u; float f; } c; c.u = (u32)v << 16;
  return c.f;
}

DEV u32 cvtpk(float lo, float hi) {  // packed f32x2 -> bf16x2 (RNE)
  u32 r;
  asm("v_cvt_pk_bf16_f32 %0, %1, %2" : "=v"(r) : "v"(lo), "v"(hi));
  return r;
}

DEV float gelu_tanh(float v) {
  const float c0 = 0.7978845608028654f;  // sqrt(2/pi)
  float u = c0 * (v + 0.044715f * v * v * v);
  return 0.5f * v * (1.0f + tanhf(u));
}

// ---- chunk bookkeeping -----------------------------------------------------
// q-tile t in [0,128) has nt = t/4+1 key-tiles, split into chunks of 8 at
// k-band c (tiles [8c, min(8c+8, nt))). Chunk exists iff t >= 32c.
// "strip" chunk: (t>>5)==c, len v = (t-32c)/4+1, contains the diagonal.
// interior chunk: (t>>5)>c, len 8, no diagonal.
// Pairs (160/bh): p<96 -> two interior chunks (enumeration below);
// p>=96 -> strip pair (32c+i, c) & (32(c+2)+i, c+2), equal len.
DEV void dec_unit(int idx, int& t, int& c) {  // interior unit enumeration
  if (idx < 32) { t = 32 + idx; c = 0; }
  else if (idx < 96) { t = 64 + ((idx - 32) >> 1); c = (idx - 32) & 1; }
  else { int q = idx - 96; int d = q / 3; t = 96 + d; c = q - 3 * d; }
}

DEV int uid_of(int t, int c) {  // inverse map: chunk -> partial slot
  if ((t >> 5) == c) {          // strip
    int i = t - (c << 5), v = (i >> 2) + 1, j = i & 3;
    int pp = 96 + ((8 - v) << 3) + ((c & 1) << 2) + j;
    return 2 * pp + (c >> 1);
  }
  if (t < 64) return t - 32;
  if (t < 96) return 32 + ((t - 64) << 1) + c;
  return 96 + (t - 96) * 3 + c;
}

// ---------- transpose + convert: W fp32 [K,N] -> Wt bf16 [N,K] -------------
__global__ __launch_bounds__(256) void tconv_kernel(
    const float* __restrict__ W, u16* __restrict__ Wt, int K, int N) {
  __shared__ u16 T[64][80];
  const int t = threadIdx.x;
  const int n0 = blockIdx.x * 64, k0 = blockIdx.y * 64;
  const int kr = t >> 4, nc = (t & 15) * 4;
#pragma unroll
  for (int p = 0; p < 4; ++p) {
    const int k = p * 16 + kr;
    float4 v = *(const float4*)(W + (size_t)(k0 + k) * N + n0 + nc);
    T[nc + 0][k] = f2bf(v.x);
    T[nc + 1][k] = f2bf(v.y);
    T[nc + 2][k] = f2bf(v.z);
    T[nc + 3][k] = f2bf(v.w);
  }
  __syncthreads();
  const int nr = t >> 2, kc = (t & 3) * 16;
  *(s16x8*)(Wt + (size_t)(n0 + nr) * K + k0 + kc) = *(const s16x8*)&T[nr][kc];
  *(s16x8*)(Wt + (size_t)(n0 + nr) * K + k0 + kc + 8) =
      *(const s16x8*)&T[nr][kc + 8];
}

// ---------------- LayerNorm: fp32 [rows,1024] -> bf16 [rows,1024] ----------
__global__ __launch_bounds__(256) void ln_kernel(
    const float* __restrict__ x, const float* __restrict__ g,
    const float* __restrict__ b, u16* __restrict__ out) {
  const int row = blockIdx.x;
  const int t = threadIdx.x;
  const float* xr = x + (size_t)row * 1024;
  float4 v = *(const float4*)(xr + t * 4);
  float s = v.x + v.y + v.z + v.w;
  float ss = v.x * v.x + v.y * v.y + v.z * v.z + v.w * v.w;
#pragma unroll
  for (int off = 1; off < 64; off <<= 1) {
    s += __shfl_xor(s, off);
    ss += __shfl_xor(ss, off);
  }
  __shared__ float sb[4], ssb[4];
  const int w = t >> 6;
  if ((t & 63) == 0) { sb[w] = s; ssb[w] = ss; }
  __syncthreads();
  s = sb[0] + sb[1] + sb[2] + sb[3];
  ss = ssb[0] + ssb[1] + ssb[2] + ssb[3];
  const float mean = s * (1.0f / 1024.0f);
  const float var = ss * (1.0f / 1024.0f) - mean * mean;
  const float rstd = rsqrtf(var + 1e-5f);
  const int c = t * 4;
  ushort4 o;
  o.x = f2bf(g[c + 0] * ((v.x - mean) * rstd) + b[c + 0]);
  o.y = f2bf(g[c + 1] * ((v.y - mean) * rstd) + b[c + 1]);
  o.z = f2bf(g[c + 2] * ((v.z - mean) * rstd) + b[c + 2]);
  o.w = f2bf(g[c + 3] * ((v.w - mean) * rstd) + b[c + 3]);
  *(ushort4*)(out + (size_t)row * 1024 + c) = o;
}

// ---------------- GEMM: C[M,N] = A(bf16)[M,K] @ Bt(bf16)[N,K]^T ------------
template <int EPI>
__global__ __launch_bounds__(256) void gemm_kernel(
    const u16* __restrict__ A, const u16* __restrict__ Bt,
    const float* __restrict__ bias, const float* __restrict__ res,
    void* __restrict__ Cv, int M, int N, int K) {
  __shared__ __align__(16) u16 Al[128][32];
  __shared__ __align__(16) u16 Bl[128][32];
  const int t = threadIdx.x;
  const int lane = t & 63, w = t >> 6;
  const int wm = (w >> 1) * 64, wn = (w & 1) * 64;
  const int bm = blockIdx.y * 128, bn = blockIdx.x * 128;
  const int lr = lane & 15, lg = lane >> 4;
  const int srow = lane >> 2, scol = (lane & 3) * 8;
  f32x4 acc[4][4] = {};

  for (int kt = 0; kt < K; kt += 32) {
    __syncthreads();
#pragma unroll
    for (int p = 0; p < 2; ++p) {
      const int r0 = (w * 2 + p) * 16;
      GLOAD_LDS16(A + (size_t)(bm + r0 + srow) * K + kt + scol, &Al[r0][0]);
      GLOAD_LDS16(Bt + (size_t)(bn + r0 + srow) * K + kt + scol, &Bl[r0][0]);
    }
    __syncthreads();
    s16x8 af[4], bf[4];
#pragma unroll
    for (int i = 0; i < 4; ++i) {
      af[i] = *(const s16x8*)&Al[wm + i * 16 + lr][lg * 8];
      bf[i] = *(const s16x8*)&Bl[wn + i * 16 + lr][lg * 8];
    }
#pragma unroll
    for (int i = 0; i < 4; ++i)
#pragma unroll
      for (int j = 0; j < 4; ++j)
        acc[i][j] = MFMA16(af[i], bf[j], acc[i][j], 0, 0, 0);
  }

#pragma unroll
  for (int i = 0; i < 4; ++i) {
    const int row = bm + wm + i * 16 + lg * 4;  // + e
#pragma unroll
    for (int j = 0; j < 4; ++j) {
      const int col = bn + wn + j * 16 + lr;
      if (EPI == 0) {
        const int bb = row >> 11, sloc = row & 2047;
        const int which = col >> 10, n = col & 1023;
        const int hh = n >> 6, dd = n & 63;
        u16* qbuf = (u16*)Cv;
        if (which == 2) {  // V transposed [bh][64][2048]
          ushort4 o;
          o.x = f2bf(acc[i][j][0]); o.y = f2bf(acc[i][j][1]);
          o.z = f2bf(acc[i][j][2]); o.w = f2bf(acc[i][j][3]);
          *(ushort4*)(qbuf + 8388608 +
                      (size_t)((bb * 16 + hh) * 64 + dd) * 2048 + sloc) = o;
        } else {
          // q pre-scaled by (1/8)*log2(e) so attention runs in exp2 space
          const float sc = (which == 0) ? 0.18033688011112042f : 1.0f;
          u16* dst = qbuf + (size_t)which * 4194304 +
                     ((size_t)(bb * 16 + hh) * 2048 + sloc) * 64 + dd;
#pragma unroll
          for (int e = 0; e < 4; ++e) dst[(size_t)e * 64] = f2bf(acc[i][j][e] * sc);
        }
      } else if (EPI == 1) {
        float* C = (float*)Cv;
        const float bs = bias[col];
#pragma unroll
        for (int e = 0; e < 4; ++e)
          C[(size_t)(row + e) * N + col] =
              acc[i][j][e] + bs + res[(size_t)(row + e) * N + col];
      } else {
        u16* C = (u16*)Cv;
        const float bs = bias[col];
#pragma unroll
        for (int e = 0; e < 4; ++e)
          C[(size_t)(row + e) * N + col] = f2bf(gelu_tanh(acc[i][j][e] + bs));
      }
    }
  }
}

// ---------------- Flash attention: chunked split-K, dual lockstep chains ---
// Qg,Kg: [32][2048][64] bf16 (q pre-scaled to exp2 space); Vt: [32][64][2048].
// Block = 256 thr = 4 independent waves; wave = pair p = blockIdx.x*4 + w.
struct AttnChain {
  s16x8 aq0, aq1;   // Q[q=lr][d=lg*8+j], halves d<32 / d>=32
  f32x4 acco[4];    // O[q=lr][d = c*16 + lg*4 + e]
  float m, l;       // running max / denom for row q=lr (log2 space)
};

template <bool DIAG>
DEV void attn_tile(AttnChain& st, int k0, int qs, const u16* Kbase,
                   const u16* Vbase, u32* Prow, int lr, int lg, int swz) {
  s16x8 kb0[4], kb1[4];
#pragma unroll
  for (int s = 0; s < 4; ++s) {
    const u16* kp = Kbase + (size_t)(k0 + s * 16 + lr) * 64 + lg * 8;
    kb0[s] = *(const s16x8*)kp;
    kb1[s] = *(const s16x8*)(kp + 32);
  }
  f32x4 sc[4];
#pragma unroll
  for (int s = 0; s < 4; ++s) {
    f32x4 a = {};
    a = MFMA16(kb0[s], st.aq0, a, 0, 0, 0);
    a = MFMA16(kb1[s], st.aq1, a, 0, 0, 0);
    sc[s] = a;
  }
  s16x8 vb0[4], vb1[4];
#pragma unroll
  for (int c = 0; c < 4; ++c) {
    const u16* vp = Vbase + (size_t)(c * 16 + lr) * 2048 + k0 + lg * 8;
    vb0[c] = *(const s16x8*)vp;
    vb1[c] = *(const s16x8*)(vp + 32);
  }
  if (DIAG) {
#pragma unroll
    for (int s = 0; s < 4; ++s)
#pragma unroll
      for (int e = 0; e < 4; ++e)
        if (k0 + s * 16 + lg * 4 + e > qs + lr) sc[s][e] = -INFINITY;
  }
  float mt = fmaxf(fmaxf(sc[0][0], sc[0][1]), fmaxf(sc[0][2], sc[0][3]));
#pragma unroll
  for (int s = 1; s < 4; ++s)
    mt = fmaxf(mt, fmaxf(fmaxf(sc[s][0], sc[s][1]), fmaxf(sc[s][2], sc[s][3])));
  mt = fmaxf(mt, __shfl_xor(mt, 16));
  mt = fmaxf(mt, __shfl_xor(mt, 32));
  const float mn = fmaxf(st.m, mt);
  const float sf = exp2f(st.m - mn);
  float p[4][4];
  float rs = 0.f;
#pragma unroll
  for (int s = 0; s < 4; ++s)
#pragma unroll
    for (int e = 0; e < 4; ++e) {
      p[s][e] = exp2f(sc[s][e] - mn);
      rs += p[s][e];
    }
  rs += __shfl_xor(rs, 16);
  rs += __shfl_xor(rs, 32);
  st.l = st.l * sf + rs;
  st.m = mn;
#pragma unroll
  for (int s = 0; s < 4; ++s) {
    uint2 wv;
    wv.x = cvtpk(p[s][0], p[s][1]);
    wv.y = cvtpk(p[s][2], p[s][3]);
    *(uint2*)&Prow[(s * 8 + lg * 2) ^ swz] = wv;
  }
  const s16x8 pa0 = *(const s16x8*)&Prow[(lg * 4) ^ swz];
  const s16x8 pa1 = *(const s16x8*)&Prow[(16 + lg * 4) ^ swz];
#pragma unroll
  for (int c = 0; c < 4; ++c) {
    f32x4 a = st.acco[c];
    a[0] *= sf; a[1] *= sf; a[2] *= sf; a[3] *= sf;
    st.acco[c] = a;
  }
#pragma unroll
  for (int c = 0; c < 4; ++c) {
    st.acco[c] = MFMA16(vb0[c], pa0, st.acco[c], 0, 0, 0);
    st.acco[c] = MFMA16(vb1[c], pa1, st.acco[c], 0, 0, 0);
  }
}

DEV void attn_init(AttnChain& st, const u16* Qbase, int qs, int lr, int lg) {
  const u16* qp = Qbase + (size_t)(qs + lr) * 64 + lg * 8;
  st.aq0 = *(const s16x8*)qp;
  st.aq1 = *(const s16x8*)(qp + 32);
  st.m = -INFINITY;
  st.l = 0.f;
#pragma unroll
  for (int c = 0; c < 4; ++c) st.acco[c] = f32x4{};
}

DEV void attn_emit(const AttnChain& st, u16* __restrict__ pO,
                   float* __restrict__ pml, int uid, int lr, int lg) {
  u16* po = pO + (size_t)uid * 1024 + lr * 64 + lg * 4;
#pragma unroll
  for (int c = 0; c < 4; ++c) {
    uint2 o;
    o.x = cvtpk(st.acco[c][0], st.acco[c][1]);
    o.y = cvtpk(st.acco[c][2], st.acco[c][3]);
    *(uint2*)(po + c * 16) = o;
  }
  if (lg == 0) {
    pml[uid * 32 + lr] = st.m;
    pml[uid * 32 + 16 + lr] = st.l;
  }
}

__global__ __launch_bounds__(256) void attn_kernel(
    const u16* __restrict__ Qg, const u16* __restrict__ Kg,
    const u16* __restrict__ Vt, u16* __restrict__ pO,
    float* __restrict__ pml) {
  __shared__ __align__(16) u32 P32[4][2][16][32];
  const int w = threadIdx.x >> 6, lane = threadIdx.x & 63;
  const int p = blockIdx.x * 4 + w, bh = blockIdx.y;
  const int lr = lane & 15, lg = lane >> 4;
  const int swz = (lr & 7) << 2;

  int tA, cA, tB, cB, L;
  bool strip;
  if (p < 96) {
    dec_unit(2 * p, tA, cA);
    dec_unit(2 * p + 1, tB, cB);
    L = 8; strip = false;
  } else {
    const int q = p - 96;
    const int v = 8 - (q >> 3), r = q & 7, c = r >> 2, j = r & 3;
    const int i4 = 4 * (v - 1) + j;
    tA = 32 * c + i4; cA = c;
    tB = 32 * (c + 2) + i4; cB = c + 2;
    L = v; strip = true;
  }
  const int qsA = tA * 16, qsB = tB * 16;
  const size_t baseK = (size_t)bh * 2048 * 64;
  const size_t baseV = (size_t)bh * 64 * 2048;
  const u16* Kb = Kg + baseK;
  const u16* Vb = Vt + baseV;
  u32* PrA = &P32[w][0][lr][0];
  u32* PrB = &P32[w][1][lr][0];

  AttnChain A, B;
  attn_init(A, Qg + baseK, qsA, lr, lg);
  attn_init(B, Qg + baseK, qsB, lr, lg);

  for (int i = 0; i < L - 1; ++i) {
    attn_tile<false>(B, (8 * cB + i) * 64, qsB, Kb, Vb, PrB, lr, lg, swz);
    attn_tile<false>(A, (8 * cA + i) * 64, qsA, Kb, Vb, PrA, lr, lg, swz);
  }
  if (strip) {
    attn_tile<true>(B, (8 * cB + L - 1) * 64, qsB, Kb, Vb, PrB, lr, lg, swz);
    attn_tile<true>(A, (8 * cA + L - 1) * 64, qsA, Kb, Vb, PrA, lr, lg, swz);
  } else {
    attn_tile<false>(B, (8 * cB + L - 1) * 64, qsB, Kb, Vb, PrB, lr, lg, swz);
    attn_tile<false>(A, (8 * cA + L - 1) * 64, qsA, Kb, Vb, PrA, lr, lg, swz);
  }
  const int ub = bh * 320;
  attn_emit(A, pO, pml, ub + 2 * p, lr, lg);
  attn_emit(B, pO, pml, ub + 2 * p + 1, lr, lg);
}

// ---------------- combine chunk partials -> ctx bf16 -----------------------
__global__ __launch_bounds__(64) void attn_combine(
    const u16* __restrict__ pO, const float* __restrict__ pml,
    u16* __restrict__ ctx) {
  const int t = blockIdx.x, bh = blockIdx.y;
  const int lane = threadIdx.x & 63;
  const int nc = (t >> 5) + 1;
  int uids[4];
  for (int c = 0; c < 4; ++c)
    uids[c] = (c < nc) ? (bh * 320 + uid_of(t, c)) : 0;
  const int rbase = (lane >> 4) << 2, col = (lane & 15) * 4;
  const int bb = bh >> 4, hh = bh & 15;
#pragma unroll
  for (int rr = 0; rr < 4; ++rr) {
    const int r = rbase + rr;
    float M = -INFINITY;
    float mm[4], ll[4];
    for (int c = 0; c < nc; ++c) {
      mm[c] = pml[uids[c] * 32 + r];
      ll[c] = pml[uids[c] * 32 + 16 + r];
      M = fmaxf(M, mm[c]);
    }
    float den = 0.f;
    float acc0 = 0.f, acc1 = 0.f, acc2 = 0.f, acc3 = 0.f;
    for (int c = 0; c < nc; ++c) {
      const float wgt = exp2f(mm[c] - M);
      den += ll[c] * wgt;
      ushort4 a = *(const ushort4*)(pO + (size_t)uids[c] * 1024 + r * 64 + col);
      acc0 += bf2f(a.x) * wgt;
      acc1 += bf2f(a.y) * wgt;
      acc2 += bf2f(a.z) * wgt;
      acc3 += bf2f(a.w) * wgt;
    }
    const float inv = 1.0f / den;
    ushort4 o;
    o.x = f2bf(acc0 * inv);
    o.y = f2bf(acc1 * inv);
    o.z = f2bf(acc2 * inv);
    o.w = f2bf(acc3 * inv);
    const int q = t * 16 + r;
    *(ushort4*)(ctx + (size_t)(bb * 2048 + q) * 1024 + hh * 64 + col) = o;
  }
}

// ---------------------------------------------------------------------------
extern "C" void kernel_launch(void* const* d_in, const int* in_sizes, int n_in,
                              void* d_out, int out_size, void* d_ws,
                              size_t ws_size, hipStream_t stream) {
  const float* x  = (const float*)d_in[0];
  const float* wq = (const float*)d_in[1];
  const float* wk = (const float*)d_in[2];
  const float* wv = (const float*)d_in[3];
  const float* wo = (const float*)d_in[4];
  const float* bo = (const float*)d_in[5];
  const float* w1 = (const float*)d_in[6];
  const float* b1 = (const float*)d_in[7];
  const float* w2 = (const float*)d_in[8];
  const float* b2 = (const float*)d_in[9];
  const float* g1 = (const float*)d_in[10];
  const float* s1 = (const float*)d_in[11];
  const float* g2 = (const float*)d_in[12];
  const float* s2 = (const float*)d_in[13];
  float* out = (float*)d_out;

  // ws layout (MB): 0-8 hb | 8-32 qbuf | 32-40 ctxb | 40-60 pO (alias x2
  // 40-56 afterwards) | 60-62 pml | 62-68 qkvw | 68-70 wot | 70-78 w1t |
  // 78-86 w2t | 86-94 h2b | gb aliases 0-32 during FFN.
  const size_t MB = (size_t)1 << 20;
  char* p = (char*)d_ws;
  u16* hb    = (u16*)(p + 0 * MB);
  u16* qbuf  = (u16*)(p + 8 * MB);
  u16* ctxb  = (u16*)(p + 32 * MB);
  u16* pO    = (u16*)(p + 40 * MB);
  float* x2  = (float*)(p + 40 * MB);
  float* pml = (float*)(p + 60 * MB);
  u16* qkvw  = (u16*)(p + 62 * MB);
  u16* wot   = (u16*)(p + 68 * MB);
  u16* w1t   = (u16*)(p + 70 * MB);
  u16* w2t   = (u16*)(p + 78 * MB);
  u16* h2b   = (u16*)(p + 86 * MB);
  u16* gb    = (u16*)(p + 0 * MB);

  const dim3 blk(256);
  tconv_kernel<<<dim3(16, 16), blk, 0, stream>>>(wq, qkvw, 1024, 1024);
  tconv_kernel<<<dim3(16, 16), blk, 0, stream>>>(wk, qkvw + 1048576, 1024, 1024);
  tconv_kernel<<<dim3(16, 16), blk, 0, stream>>>(wv, qkvw + 2097152, 1024, 1024);
  tconv_kernel<<<dim3(16, 16), blk, 0, stream>>>(wo, wot, 1024, 1024);
  tconv_kernel<<<dim3(64, 16), blk, 0, stream>>>(w1, w1t, 1024, 4096);
  tconv_kernel<<<dim3(16, 64), blk, 0, stream>>>(w2, w2t, 4096, 1024);

  ln_kernel<<<4096, blk, 0, stream>>>(x, g1, s1, hb);
  gemm_kernel<0><<<dim3(24, 32), blk, 0, stream>>>(hb, qkvw, nullptr, nullptr,
                                                   qbuf, 4096, 3072, 1024);
  attn_kernel<<<dim3(40, 32), blk, 0, stream>>>(
      qbuf, qbuf + 4194304, qbuf + 8388608, pO, pml);
  attn_combine<<<dim3(128, 32), dim3(64), 0, stream>>>(pO, pml, ctxb);
  gemm_kernel<1><<<dim3(8, 32), blk, 0, stream>>>(ctxb, wot, bo, x, x2, 4096,
                                                  1024, 1024);
  ln_kernel<<<4096, blk, 0, stream>>>(x2, g2, s2, h2b);
  gemm_kernel<2><<<dim3(32, 32), blk, 0, stream>>>(h2b, w1t, b1, nullptr, gb,
                                                   4096, 4096, 1024);
  gemm_kernel<1><<<dim3(8, 32), blk, 0, stream>>>(gb, w2t, b2, x2, out, 4096,
                                                  1024, 4096);
}

// Round 7
// 375.250 us; speedup vs baseline: 1.1744x; 1.1744x over previous
//
#include <hip/hip_runtime.h>

// TransformerBlock: B=2, S=2048, D=1024, H=16, dh=64, FFN=4096.
// Round 7: round-4 attention (proven) + double-buffered prefetch GEMM
// (2-phase pipeline: stage(kt+1) overlaps compute(kt), 1 barrier/K-step).

typedef __attribute__((ext_vector_type(8))) short s16x8;
typedef __attribute__((ext_vector_type(4))) float f32x4;
typedef unsigned short u16;
typedef unsigned int u32;

#define DEV static __device__ __forceinline__
#define MFMA16 __builtin_amdgcn_mfma_f32_16x16x32_bf16
#define GLOAD_LDS16(gp, lp)                                         \
  __builtin_amdgcn_global_load_lds(                                 \
      (const __attribute__((address_space(1))) void*)(gp),          \
      (__attribute__((address_space(3))) void*)(lp), 16, 0, 0)

DEV u16 f2bf(float f) {
  union { float f; unsigned u; } c; c.f = f;
  unsigned u = c.u;
  u += 0x7fff + ((u >> 16) & 1);   // RNE
  return (u16)(u >> 16);
}

DEV u32 cvtpk(float lo, float hi) {  // packed f32x2 -> bf16x2 (RNE)
  u32 r;
  asm("v_cvt_pk_bf16_f32 %0, %1, %2" : "=v"(r) : "v"(lo), "v"(hi));
  return r;
}

DEV float gelu_tanh(float v) {
  const float c0 = 0.7978845608028654f;  // sqrt(2/pi)
  float u = c0 * (v + 0.044715f * v * v * v);
  return 0.5f * v * (1.0f + tanhf(u));
}

// ---------- transpose + convert: W fp32 [K,N] -> Wt bf16 [N,K] -------------
__global__ __launch_bounds__(256) void tconv_kernel(
    const float* __restrict__ W, u16* __restrict__ Wt, int K, int N) {
  __shared__ u16 T[64][80];
  const int t = threadIdx.x;
  const int n0 = blockIdx.x * 64, k0 = blockIdx.y * 64;
  const int kr = t >> 4, nc = (t & 15) * 4;
#pragma unroll
  for (int p = 0; p < 4; ++p) {
    const int k = p * 16 + kr;
    float4 v = *(const float4*)(W + (size_t)(k0 + k) * N + n0 + nc);
    T[nc + 0][k] = f2bf(v.x);
    T[nc + 1][k] = f2bf(v.y);
    T[nc + 2][k] = f2bf(v.z);
    T[nc + 3][k] = f2bf(v.w);
  }
  __syncthreads();
  const int nr = t >> 2, kc = (t & 3) * 16;
  *(s16x8*)(Wt + (size_t)(n0 + nr) * K + k0 + kc) = *(const s16x8*)&T[nr][kc];
  *(s16x8*)(Wt + (size_t)(n0 + nr) * K + k0 + kc + 8) =
      *(const s16x8*)&T[nr][kc + 8];
}

// ---------------- LayerNorm: fp32 [rows,1024] -> bf16 [rows,1024] ----------
__global__ __launch_bounds__(256) void ln_kernel(
    const float* __restrict__ x, const float* __restrict__ g,
    const float* __restrict__ b, u16* __restrict__ out) {
  const int row = blockIdx.x;
  const int t = threadIdx.x;
  const float* xr = x + (size_t)row * 1024;
  float4 v = *(const float4*)(xr + t * 4);
  float s = v.x + v.y + v.z + v.w;
  float ss = v.x * v.x + v.y * v.y + v.z * v.z + v.w * v.w;
#pragma unroll
  for (int off = 1; off < 64; off <<= 1) {
    s += __shfl_xor(s, off);
    ss += __shfl_xor(ss, off);
  }
  __shared__ float sb[4], ssb[4];
  const int w = t >> 6;
  if ((t & 63) == 0) { sb[w] = s; ssb[w] = ss; }
  __syncthreads();
  s = sb[0] + sb[1] + sb[2] + sb[3];
  ss = ssb[0] + ssb[1] + ssb[2] + ssb[3];
  const float mean = s * (1.0f / 1024.0f);
  const float var = ss * (1.0f / 1024.0f) - mean * mean;
  const float rstd = rsqrtf(var + 1e-5f);
  const int c = t * 4;
  ushort4 o;
  o.x = f2bf(g[c + 0] * ((v.x - mean) * rstd) + b[c + 0]);
  o.y = f2bf(g[c + 1] * ((v.y - mean) * rstd) + b[c + 1]);
  o.z = f2bf(g[c + 2] * ((v.z - mean) * rstd) + b[c + 2]);
  o.w = f2bf(g[c + 3] * ((v.w - mean) * rstd) + b[c + 3]);
  *(ushort4*)(out + (size_t)row * 1024 + c) = o;
}

// ---------------- GEMM: C[M,N] = A(bf16)[M,K] @ Bt(bf16)[N,K]^T ------------
// Double-buffered LDS: stage(kt+1) issued before compute(kt), 1 barrier/step.
DEV void gemm_stage(const u16* __restrict__ A, const u16* __restrict__ Bt,
                    int bm, int bn, int K, int kof, u16 (*Al)[32],
                    u16 (*Bl)[32], int w, int srow, int scol) {
#pragma unroll
  for (int p = 0; p < 2; ++p) {
    const int r0 = (w * 2 + p) * 16;
    GLOAD_LDS16(A + (size_t)(bm + r0 + srow) * K + kof + scol, &Al[r0][0]);
    GLOAD_LDS16(Bt + (size_t)(bn + r0 + srow) * K + kof + scol, &Bl[r0][0]);
  }
}

DEV void gemm_step(const u16 (*Al)[32], const u16 (*Bl)[32],
                   f32x4 (&acc)[4][4], int wm, int wn, int lr, int lg) {
  s16x8 af[4], bf[4];
#pragma unroll
  for (int i = 0; i < 4; ++i) {
    af[i] = *(const s16x8*)&Al[wm + i * 16 + lr][lg * 8];
    bf[i] = *(const s16x8*)&Bl[wn + i * 16 + lr][lg * 8];
  }
#pragma unroll
  for (int i = 0; i < 4; ++i)
#pragma unroll
    for (int j = 0; j < 4; ++j)
      acc[i][j] = MFMA16(af[i], bf[j], acc[i][j], 0, 0, 0);
}

template <int EPI>
__global__ __launch_bounds__(256) void gemm_kernel(
    const u16* __restrict__ A, const u16* __restrict__ Bt,
    const float* __restrict__ bias, const float* __restrict__ res,
    void* __restrict__ Cv, int M, int N, int K) {
  __shared__ __align__(16) u16 Al[2][128][32];
  __shared__ __align__(16) u16 Bl[2][128][32];
  const int t = threadIdx.x;
  const int lane = t & 63, w = t >> 6;
  const int wm = (w >> 1) * 64, wn = (w & 1) * 64;
  const int bm = blockIdx.y * 128, bn = blockIdx.x * 128;
  const int lr = lane & 15, lg = lane >> 4;
  const int srow = lane >> 2, scol = (lane & 3) * 8;
  f32x4 acc[4][4] = {};
  const int nkt = K >> 5;

  gemm_stage(A, Bt, bm, bn, K, 0, Al[0], Bl[0], w, srow, scol);
  __syncthreads();
  for (int kt = 0; kt < nkt - 1; ++kt) {
    const int cur = kt & 1;
    gemm_stage(A, Bt, bm, bn, K, (kt + 1) << 5, Al[cur ^ 1], Bl[cur ^ 1], w,
               srow, scol);
    gemm_step(Al[cur], Bl[cur], acc, wm, wn, lr, lg);
    __syncthreads();
  }
  gemm_step(Al[(nkt - 1) & 1], Bl[(nkt - 1) & 1], acc, wm, wn, lr, lg);

#pragma unroll
  for (int i = 0; i < 4; ++i) {
    const int row = bm + wm + i * 16 + lg * 4;  // + e
#pragma unroll
    for (int j = 0; j < 4; ++j) {
      const int col = bn + wn + j * 16 + lr;
      if (EPI == 0) {
        const int bb = row >> 11, sloc = row & 2047;
        const int which = col >> 10, n = col & 1023;
        const int hh = n >> 6, dd = n & 63;
        u16* qbuf = (u16*)Cv;
        if (which == 2) {  // V transposed [bh][64][2048]
          ushort4 o;
          o.x = f2bf(acc[i][j][0]); o.y = f2bf(acc[i][j][1]);
          o.z = f2bf(acc[i][j][2]); o.w = f2bf(acc[i][j][3]);
          *(ushort4*)(qbuf + 8388608 +
                      (size_t)((bb * 16 + hh) * 64 + dd) * 2048 + sloc) = o;
        } else {
          // q pre-scaled by (1/8)*log2(e) so attention runs in exp2 space
          const float sc = (which == 0) ? 0.18033688011112042f : 1.0f;
          u16* dst = qbuf + (size_t)which * 4194304 +
                     ((size_t)(bb * 16 + hh) * 2048 + sloc) * 64 + dd;
#pragma unroll
          for (int e = 0; e < 4; ++e) dst[(size_t)e * 64] = f2bf(acc[i][j][e] * sc);
        }
      } else if (EPI == 1) {
        float* C = (float*)Cv;
        const float bs = bias[col];
#pragma unroll
        for (int e = 0; e < 4; ++e)
          C[(size_t)(row + e) * N + col] =
              acc[i][j][e] + bs + res[(size_t)(row + e) * N + col];
      } else {
        u16* C = (u16*)Cv;
        const float bs = bias[col];
#pragma unroll
        for (int e = 0; e < 4; ++e)
          C[(size_t)(row + e) * N + col] = f2bf(gelu_tanh(acc[i][j][e] + bs));
      }
    }
  }
}

// ---------------- Flash attention: swapped-operand, dual-chain (round 4) ---
// Qg,Kg: [32][2048][64] bf16 (q pre-scaled to exp2 space); Vt: [32][64][2048].
// Block = 1 wave; chain A = q-tile wx, chain B = q-tile 127-wx.
struct AttnChain {
  s16x8 aq0, aq1;   // Q[q=lr][d=lg*8+j], halves d<32 / d>=32
  f32x4 acco[4];    // O[q=lr][d = c*16 + lg*4 + e]
  float m, l;       // running max / denom for row q=lr (log2 space)
};

template <bool DIAG>
DEV void attn_tile(AttnChain& st, int k0, int qs, const u16* Kbase,
                   const u16* Vbase, u32* Prow, int lr, int lg, int swz) {
  s16x8 kb0[4], kb1[4];
#pragma unroll
  for (int s = 0; s < 4; ++s) {
    const u16* kp = Kbase + (size_t)(k0 + s * 16 + lr) * 64 + lg * 8;
    kb0[s] = *(const s16x8*)kp;
    kb1[s] = *(const s16x8*)(kp + 32);
  }
  f32x4 sc[4];
#pragma unroll
  for (int s = 0; s < 4; ++s) {
    f32x4 a = {};
    a = MFMA16(kb0[s], st.aq0, a, 0, 0, 0);
    a = MFMA16(kb1[s], st.aq1, a, 0, 0, 0);
    sc[s] = a;
  }
  s16x8 vb0[4], vb1[4];
#pragma unroll
  for (int c = 0; c < 4; ++c) {
    const u16* vp = Vbase + (size_t)(c * 16 + lr) * 2048 + k0 + lg * 8;
    vb0[c] = *(const s16x8*)vp;
    vb1[c] = *(const s16x8*)(vp + 32);
  }
  if (DIAG) {
#pragma unroll
    for (int s = 0; s < 4; ++s)
#pragma unroll
      for (int e = 0; e < 4; ++e)
        if (k0 + s * 16 + lg * 4 + e > qs + lr) sc[s][e] = -INFINITY;
  }
  float mt = fmaxf(fmaxf(sc[0][0], sc[0][1]), fmaxf(sc[0][2], sc[0][3]));
#pragma unroll
  for (int s = 1; s < 4; ++s)
    mt = fmaxf(mt, fmaxf(fmaxf(sc[s][0], sc[s][1]), fmaxf(sc[s][2], sc[s][3])));
  mt = fmaxf(mt, __shfl_xor(mt, 16));
  mt = fmaxf(mt, __shfl_xor(mt, 32));
  const float mn = fmaxf(st.m, mt);
  const float sf = exp2f(st.m - mn);
  float p[4][4];
  float rs = 0.f;
#pragma unroll
  for (int s = 0; s < 4; ++s)
#pragma unroll
    for (int e = 0; e < 4; ++e) {
      p[s][e] = exp2f(sc[s][e] - mn);
      rs += p[s][e];
    }
  rs += __shfl_xor(rs, 16);
  rs += __shfl_xor(rs, 32);
  st.l = st.l * sf + rs;
  st.m = mn;
#pragma unroll
  for (int s = 0; s < 4; ++s) {
    uint2 wv;
    wv.x = cvtpk(p[s][0], p[s][1]);
    wv.y = cvtpk(p[s][2], p[s][3]);
    *(uint2*)&Prow[(s * 8 + lg * 2) ^ swz] = wv;
  }
  const s16x8 pa0 = *(const s16x8*)&Prow[(lg * 4) ^ swz];
  const s16x8 pa1 = *(const s16x8*)&Prow[(16 + lg * 4) ^ swz];
#pragma unroll
  for (int c = 0; c < 4; ++c) {
    f32x4 a = st.acco[c];
    a[0] *= sf; a[1] *= sf; a[2] *= sf; a[3] *= sf;
    st.acco[c] = a;
  }
#pragma unroll
  for (int c = 0; c < 4; ++c) {
    st.acco[c] = MFMA16(vb0[c], pa0, st.acco[c], 0, 0, 0);
    st.acco[c] = MFMA16(vb1[c], pa1, st.acco[c], 0, 0, 0);
  }
}

DEV void attn_init(AttnChain& st, const u16* Qbase, int qs, int lr, int lg) {
  const u16* qp = Qbase + (size_t)(qs + lr) * 64 + lg * 8;
  st.aq0 = *(const s16x8*)qp;
  st.aq1 = *(const s16x8*)(qp + 32);
  st.m = -INFINITY;
  st.l = 0.f;
#pragma unroll
  for (int c = 0; c < 4; ++c) st.acco[c] = f32x4{};
}

DEV void attn_fin(const AttnChain& st, u16* __restrict__ ctx, int bh, int qs,
                  int lr, int lg) {
  const int bb = bh >> 4, hh = bh & 15;
  const float inv = 1.0f / st.l;
  const size_t rowoff = (size_t)(bb * 2048 + qs + lr) * 1024 + hh * 64 + lg * 4;
#pragma unroll
  for (int c = 0; c < 4; ++c) {
    uint2 o;
    o.x = cvtpk(st.acco[c][0] * inv, st.acco[c][1] * inv);
    o.y = cvtpk(st.acco[c][2] * inv, st.acco[c][3] * inv);
    *(uint2*)(ctx + rowoff + c * 16) = o;
  }
}

__global__ __launch_bounds__(64, 2) void attn_kernel(
    const u16* __restrict__ Qg, const u16* __restrict__ Kg,
    const u16* __restrict__ Vt, u16* __restrict__ ctx) {
  __shared__ __align__(16) u32 P32[2][16][32];
  const int lane = threadIdx.x & 63;
  const int wx = blockIdx.x, bh = blockIdx.y;
  const int lr = lane & 15, lg = lane >> 4;
  const int swz = (lr & 7) << 2;
  const int tA = wx, tB = 127 - wx;
  const int qsA = tA * 16, qsB = tB * 16;
  const int ntA = tA / 4 + 1, ntB = tB / 4 + 1;
  const size_t baseK = (size_t)bh * 2048 * 64;
  const size_t baseV = (size_t)bh * 64 * 2048;
  const u16* Kb = Kg + baseK;
  const u16* Vb = Vt + baseV;
  u32* PrA = &P32[0][lane & 15][0];
  u32* PrB = &P32[1][lane & 15][0];

  AttnChain A, B;
  attn_init(A, Qg + baseK, qsA, lr, lg);
  attn_init(B, Qg + baseK, qsB, lr, lg);

  for (int kt = 0; kt < ntA - 1; ++kt) {
    attn_tile<false>(B, kt * 64, qsB, Kb, Vb, PrB, lr, lg, swz);
    attn_tile<false>(A, kt * 64, qsA, Kb, Vb, PrA, lr, lg, swz);
  }
  {
    const int kt = ntA - 1;
    attn_tile<false>(B, kt * 64, qsB, Kb, Vb, PrB, lr, lg, swz);
    attn_tile<true>(A, kt * 64, qsA, Kb, Vb, PrA, lr, lg, swz);
  }
  attn_fin(A, ctx, bh, qsA, lr, lg);
  for (int kt = ntA; kt < ntB - 1; ++kt)
    attn_tile<false>(B, kt * 64, qsB, Kb, Vb, PrB, lr, lg, swz);
  attn_tile<true>(B, (ntB - 1) * 64, qsB, Kb, Vb, PrB, lr, lg, swz);
  attn_fin(B, ctx, bh, qsB, lr, lg);
}

// ---------------------------------------------------------------------------
extern "C" void kernel_launch(void* const* d_in, const int* in_sizes, int n_in,
                              void* d_out, int out_size, void* d_ws,
                              size_t ws_size, hipStream_t stream) {
  const float* x  = (const float*)d_in[0];
  const float* wq = (const float*)d_in[1];
  const float* wk = (const float*)d_in[2];
  const float* wv = (const float*)d_in[3];
  const float* wo = (const float*)d_in[4];
  const float* bo = (const float*)d_in[5];
  const float* w1 = (const float*)d_in[6];
  const float* b1 = (const float*)d_in[7];
  const float* w2 = (const float*)d_in[8];
  const float* b2 = (const float*)d_in[9];
  const float* g1 = (const float*)d_in[10];
  const float* s1 = (const float*)d_in[11];
  const float* g2 = (const float*)d_in[12];
  const float* s2 = (const float*)d_in[13];
  float* out = (float*)d_out;

  const size_t MB = (size_t)1 << 20;
  char* p = (char*)d_ws;
  u16* hb    = (u16*)(p + 0 * MB);    // LN1 out (dead after QKV)
  u16* qbuf  = (u16*)(p + 8 * MB);    // q | k [32][2048][64], vt [32][64][2048]
  u16* ctxb  = (u16*)(p + 32 * MB);
  float* x2  = (float*)(p + 40 * MB); // residual fp32 (16MB)
  u16* h2b   = (u16*)(p + 56 * MB);   // LN2 out (8MB)
  u16* qkvw  = (u16*)(p + 64 * MB);   // [3072][1024] packed Wq/Wk/Wv^T (6MB)
  u16* wot   = (u16*)(p + 70 * MB);
  u16* w1t   = (u16*)(p + 72 * MB);
  u16* w2t   = (u16*)(p + 80 * MB);
  u16* gb    = (u16*)(p + 0 * MB);    // gelu out, aliases hb/qbuf (32MB)

  const dim3 blk(256);
  tconv_kernel<<<dim3(16, 16), blk, 0, stream>>>(wq, qkvw, 1024, 1024);
  tconv_kernel<<<dim3(16, 16), blk, 0, stream>>>(wk, qkvw + 1048576, 1024, 1024);
  tconv_kernel<<<dim3(16, 16), blk, 0, stream>>>(wv, qkvw + 2097152, 1024, 1024);
  tconv_kernel<<<dim3(16, 16), blk, 0, stream>>>(wo, wot, 1024, 1024);
  tconv_kernel<<<dim3(64, 16), blk, 0, stream>>>(w1, w1t, 1024, 4096);
  tconv_kernel<<<dim3(16, 64), blk, 0, stream>>>(w2, w2t, 4096, 1024);

  ln_kernel<<<4096, blk, 0, stream>>>(x, g1, s1, hb);
  gemm_kernel<0><<<dim3(24, 32), blk, 0, stream>>>(hb, qkvw, nullptr, nullptr,
                                                   qbuf, 4096, 3072, 1024);
  attn_kernel<<<dim3(64, 32), dim3(64), 0, stream>>>(
      qbuf, qbuf + 4194304, qbuf + 8388608, ctxb);
  gemm_kernel<1><<<dim3(8, 32), blk, 0, stream>>>(ctxb, wot, bo, x, x2, 4096,
                                                  1024, 1024);
  ln_kernel<<<4096, blk, 0, stream>>>(x2, g2, s2, h2b);
  gemm_kernel<2><<<dim3(32, 32), blk, 0, stream>>>(h2b, w1t, b1, nullptr, gb,
                                                   4096, 4096, 1024);
  gemm_kernel<1><<<dim3(8, 32), blk, 0, stream>>>(gb, w2t, b2, x2, out, 4096,
                                                  1024, 4096);
}

// Round 8
// 342.021 us; speedup vs baseline: 1.2885x; 1.0972x over previous
//
#include <hip/hip_runtime.h>

// TransformerBlock: B=2, S=2048, D=1024, H=16, dh=64, FFN=4096.
// Round 8: 32x32 swapped-operand attention, softmax+P fully in-register
// (zero LDS), 32 q-rows/wave. GEMMs: round-7 double-buffered.

typedef __attribute__((ext_vector_type(8))) short s16x8;
typedef __attribute__((ext_vector_type(4))) float f32x4;
typedef __attribute__((ext_vector_type(16))) float f32x16;
typedef unsigned short u16;
typedef unsigned int u32;

#define DEV static __device__ __forceinline__
#define MFMA16 __builtin_amdgcn_mfma_f32_16x16x32_bf16
#define MFMA32 __builtin_amdgcn_mfma_f32_32x32x16_bf16
#define GLOAD_LDS16(gp, lp)                                         \
  __builtin_amdgcn_global_load_lds(                                 \
      (const __attribute__((address_space(1))) void*)(gp),          \
      (__attribute__((address_space(3))) void*)(lp), 16, 0, 0)

DEV u16 f2bf(float f) {
  union { float f; unsigned u; } c; c.f = f;
  unsigned u = c.u;
  u += 0x7fff + ((u >> 16) & 1);   // RNE
  return (u16)(u >> 16);
}

DEV u32 cvtpk(float lo, float hi) {  // packed f32x2 -> bf16x2 (RNE)
  u32 r;
  asm("v_cvt_pk_bf16_f32 %0, %1, %2" : "=v"(r) : "v"(lo), "v"(hi));
  return r;
}

DEV float gelu_tanh(float v) {
  const float c0 = 0.7978845608028654f;  // sqrt(2/pi)
  float u = c0 * (v + 0.044715f * v * v * v);
  return 0.5f * v * (1.0f + tanhf(u));
}

DEV s16x8 ld8(const u16* p) { return *(const s16x8*)p; }

// ---------- transpose + convert: W fp32 [K,N] -> Wt bf16 [N,K] -------------
__global__ __launch_bounds__(256) void tconv_kernel(
    const float* __restrict__ W, u16* __restrict__ Wt, int K, int N) {
  __shared__ u16 T[64][80];
  const int t = threadIdx.x;
  const int n0 = blockIdx.x * 64, k0 = blockIdx.y * 64;
  const int kr = t >> 4, nc = (t & 15) * 4;
#pragma unroll
  for (int p = 0; p < 4; ++p) {
    const int k = p * 16 + kr;
    float4 v = *(const float4*)(W + (size_t)(k0 + k) * N + n0 + nc);
    T[nc + 0][k] = f2bf(v.x);
    T[nc + 1][k] = f2bf(v.y);
    T[nc + 2][k] = f2bf(v.z);
    T[nc + 3][k] = f2bf(v.w);
  }
  __syncthreads();
  const int nr = t >> 2, kc = (t & 3) * 16;
  *(s16x8*)(Wt + (size_t)(n0 + nr) * K + k0 + kc) = *(const s16x8*)&T[nr][kc];
  *(s16x8*)(Wt + (size_t)(n0 + nr) * K + k0 + kc + 8) =
      *(const s16x8*)&T[nr][kc + 8];
}

// ---------------- LayerNorm: fp32 [rows,1024] -> bf16 [rows,1024] ----------
__global__ __launch_bounds__(256) void ln_kernel(
    const float* __restrict__ x, const float* __restrict__ g,
    const float* __restrict__ b, u16* __restrict__ out) {
  const int row = blockIdx.x;
  const int t = threadIdx.x;
  const float* xr = x + (size_t)row * 1024;
  float4 v = *(const float4*)(xr + t * 4);
  float s = v.x + v.y + v.z + v.w;
  float ss = v.x * v.x + v.y * v.y + v.z * v.z + v.w * v.w;
#pragma unroll
  for (int off = 1; off < 64; off <<= 1) {
    s += __shfl_xor(s, off);
    ss += __shfl_xor(ss, off);
  }
  __shared__ float sb[4], ssb[4];
  const int w = t >> 6;
  if ((t & 63) == 0) { sb[w] = s; ssb[w] = ss; }
  __syncthreads();
  s = sb[0] + sb[1] + sb[2] + sb[3];
  ss = ssb[0] + ssb[1] + ssb[2] + ssb[3];
  const float mean = s * (1.0f / 1024.0f);
  const float var = ss * (1.0f / 1024.0f) - mean * mean;
  const float rstd = rsqrtf(var + 1e-5f);
  const int c = t * 4;
  ushort4 o;
  o.x = f2bf(g[c + 0] * ((v.x - mean) * rstd) + b[c + 0]);
  o.y = f2bf(g[c + 1] * ((v.y - mean) * rstd) + b[c + 1]);
  o.z = f2bf(g[c + 2] * ((v.z - mean) * rstd) + b[c + 2]);
  o.w = f2bf(g[c + 3] * ((v.w - mean) * rstd) + b[c + 3]);
  *(ushort4*)(out + (size_t)row * 1024 + c) = o;
}

// ---------------- GEMM: C[M,N] = A(bf16)[M,K] @ Bt(bf16)[N,K]^T ------------
DEV void gemm_stage(const u16* __restrict__ A, const u16* __restrict__ Bt,
                    int bm, int bn, int K, int kof, u16 (*Al)[32],
                    u16 (*Bl)[32], int w, int srow, int scol) {
#pragma unroll
  for (int p = 0; p < 2; ++p) {
    const int r0 = (w * 2 + p) * 16;
    GLOAD_LDS16(A + (size_t)(bm + r0 + srow) * K + kof + scol, &Al[r0][0]);
    GLOAD_LDS16(Bt + (size_t)(bn + r0 + srow) * K + kof + scol, &Bl[r0][0]);
  }
}

DEV void gemm_step(const u16 (*Al)[32], const u16 (*Bl)[32],
                   f32x4 (&acc)[4][4], int wm, int wn, int lr, int lg) {
  s16x8 af[4], bf[4];
#pragma unroll
  for (int i = 0; i < 4; ++i) {
    af[i] = *(const s16x8*)&Al[wm + i * 16 + lr][lg * 8];
    bf[i] = *(const s16x8*)&Bl[wn + i * 16 + lr][lg * 8];
  }
#pragma unroll
  for (int i = 0; i < 4; ++i)
#pragma unroll
    for (int j = 0; j < 4; ++j)
      acc[i][j] = MFMA16(af[i], bf[j], acc[i][j], 0, 0, 0);
}

template <int EPI>
__global__ __launch_bounds__(256) void gemm_kernel(
    const u16* __restrict__ A, const u16* __restrict__ Bt,
    const float* __restrict__ bias, const float* __restrict__ res,
    void* __restrict__ Cv, int M, int N, int K) {
  __shared__ __align__(16) u16 Al[2][128][32];
  __shared__ __align__(16) u16 Bl[2][128][32];
  const int t = threadIdx.x;
  const int lane = t & 63, w = t >> 6;
  const int wm = (w >> 1) * 64, wn = (w & 1) * 64;
  const int bm = blockIdx.y * 128, bn = blockIdx.x * 128;
  const int lr = lane & 15, lg = lane >> 4;
  const int srow = lane >> 2, scol = (lane & 3) * 8;
  f32x4 acc[4][4] = {};
  const int nkt = K >> 5;

  gemm_stage(A, Bt, bm, bn, K, 0, Al[0], Bl[0], w, srow, scol);
  __syncthreads();
  for (int kt = 0; kt < nkt - 1; ++kt) {
    const int cur = kt & 1;
    gemm_stage(A, Bt, bm, bn, K, (kt + 1) << 5, Al[cur ^ 1], Bl[cur ^ 1], w,
               srow, scol);
    gemm_step(Al[cur], Bl[cur], acc, wm, wn, lr, lg);
    __syncthreads();
  }
  gemm_step(Al[(nkt - 1) & 1], Bl[(nkt - 1) & 1], acc, wm, wn, lr, lg);

#pragma unroll
  for (int i = 0; i < 4; ++i) {
    const int row = bm + wm + i * 16 + lg * 4;  // + e
#pragma unroll
    for (int j = 0; j < 4; ++j) {
      const int col = bn + wn + j * 16 + lr;
      if (EPI == 0) {
        const int bb = row >> 11, sloc = row & 2047;
        const int which = col >> 10, n = col & 1023;
        const int hh = n >> 6, dd = n & 63;
        u16* qbuf = (u16*)Cv;
        if (which == 2) {  // V transposed [bh][64][2048]
          ushort4 o;
          o.x = f2bf(acc[i][j][0]); o.y = f2bf(acc[i][j][1]);
          o.z = f2bf(acc[i][j][2]); o.w = f2bf(acc[i][j][3]);
          *(ushort4*)(qbuf + 8388608 +
                      (size_t)((bb * 16 + hh) * 64 + dd) * 2048 + sloc) = o;
        } else {
          // q pre-scaled by (1/8)*log2(e) so attention runs in exp2 space
          const float sc = (which == 0) ? 0.18033688011112042f : 1.0f;
          u16* dst = qbuf + (size_t)which * 4194304 +
                     ((size_t)(bb * 16 + hh) * 2048 + sloc) * 64 + dd;
#pragma unroll
          for (int e = 0; e < 4; ++e) dst[(size_t)e * 64] = f2bf(acc[i][j][e] * sc);
        }
      } else if (EPI == 1) {
        float* C = (float*)Cv;
        const float bs = bias[col];
#pragma unroll
        for (int e = 0; e < 4; ++e)
          C[(size_t)(row + e) * N + col] =
              acc[i][j][e] + bs + res[(size_t)(row + e) * N + col];
      } else {
        u16* C = (u16*)Cv;
        const float bs = bias[col];
#pragma unroll
        for (int e = 0; e < 4; ++e)
          C[(size_t)(row + e) * N + col] = f2bf(gelu_tanh(acc[i][j][e] + bs));
      }
    }
  }
}

// ---------------- Flash attention: 32x32 swapped, zero-LDS -----------------
// Qg,Kg: [32][2048][64] bf16 (q pre-scaled to exp2 space); Vt: [32][64][2048].
// 1 wave per block; wave owns 32 q-rows (q = qs + lane&31); hi = lane>>5.
// S^T via mfma32(K,Q): lane holds S[key = k0+32a+(r&3)+8*(r>>2)+4*hi][q].
// O^T via mfma32(V^T,P): lane holds O[d = (r&3)+8*(r>>2)+4*hi+32*dt][q].
DEV float vmax16(const f32x16& v) {
  float a = fmaxf(v[0], v[1]), b = fmaxf(v[2], v[3]);
  float c = fmaxf(v[4], v[5]), d = fmaxf(v[6], v[7]);
  float e = fmaxf(v[8], v[9]), f = fmaxf(v[10], v[11]);
  float g = fmaxf(v[12], v[13]), h = fmaxf(v[14], v[15]);
  a = fmaxf(a, b); c = fmaxf(c, d); e = fmaxf(e, f); g = fmaxf(g, h);
  return fmaxf(fmaxf(a, c), fmaxf(e, g));
}
DEV float vsum16(const f32x16& v) {
  float a = v[0] + v[1], b = v[2] + v[3];
  float c = v[4] + v[5], d = v[6] + v[7];
  float e = v[8] + v[9], f = v[10] + v[11];
  float g = v[12] + v[13], h = v[14] + v[15];
  a += b; c += d; e += f; g += h;
  return (a + c) + (e + g);
}

struct A32 {
  s16x8 q[4];       // Q B-frag per d-chunk
  f32x16 o0, o1;    // O^T d-tiles 0/1
  float m, l;
};

// MODE: 0 interior (64 keys), 1 full-diag (mask acc1), 2 half (32 keys, mask)
template <int MODE>
DEV void body32(A32& st, int k0, const u16* Kb, const u16* Vb, int la,
                int hi) {
  s16x8 ka0[4], ka1[4];
#pragma unroll
  for (int c = 0; c < 4; ++c)
    ka0[c] = ld8(Kb + (size_t)(k0 + la) * 64 + c * 16 + hi * 8);
  if (MODE != 2)
#pragma unroll
    for (int c = 0; c < 4; ++c)
      ka1[c] = ld8(Kb + (size_t)(k0 + 32 + la) * 64 + c * 16 + hi * 8);
  f32x16 s0, s1;
#pragma unroll
  for (int r = 0; r < 16; ++r) { s0[r] = 0.f; s1[r] = 0.f; }
#pragma unroll
  for (int c = 0; c < 4; ++c) s0 = MFMA32(ka0[c], st.q[c], s0, 0, 0, 0);
  if (MODE != 2)
#pragma unroll
    for (int c = 0; c < 4; ++c) s1 = MFMA32(ka1[c], st.q[c], s1, 0, 0, 0);
  // V^T A-frags issued before softmax (in flight)
  const int nkc = (MODE == 2) ? 2 : 4;
  s16x8 va0[4], va1[4];
#pragma unroll
  for (int kc = 0; kc < 4; ++kc)
    if (kc < nkc) {
      va0[kc] = ld8(Vb + (size_t)la * 2048 + k0 + kc * 16 + hi * 8);
      va1[kc] = ld8(Vb + (size_t)(32 + la) * 2048 + k0 + kc * 16 + hi * 8);
    }
  if (MODE == 1) {
#pragma unroll
    for (int r = 0; r < 16; ++r) {
      const int kl = (r & 3) + 8 * (r >> 2) + 4 * hi;
      if (kl > la) s1[r] = -INFINITY;
    }
  }
  if (MODE == 2) {
#pragma unroll
    for (int r = 0; r < 16; ++r) {
      const int kl = (r & 3) + 8 * (r >> 2) + 4 * hi;
      if (kl > la) s0[r] = -INFINITY;
    }
  }
  float mt = vmax16(s0);
  if (MODE != 2) mt = fmaxf(mt, vmax16(s1));
  mt = fmaxf(mt, __shfl_xor(mt, 32));
  const float mn = fmaxf(st.m, mt);
  const float sf = exp2f(st.m - mn);
#pragma unroll
  for (int r = 0; r < 16; ++r) s0[r] = exp2f(s0[r] - mn);
  if (MODE != 2)
#pragma unroll
    for (int r = 0; r < 16; ++r) s1[r] = exp2f(s1[r] - mn);
  float rs = vsum16(s0);
  if (MODE != 2) rs += vsum16(s1);
  rs += __shfl_xor(rs, 32);
  st.l = st.l * sf + rs;
  st.m = mn;
#pragma unroll
  for (int r = 0; r < 16; ++r) { st.o0[r] *= sf; st.o1[r] *= sf; }
  // pack P -> bf16, exchange hi-halves, PV MFMAs.
  // B-frag(kc): hi=0: [w0,w1, ptn w0, ptn w1]; hi=1: [ptn w2, ptn w3, w2, w3]
  const int nh = (MODE == 2) ? 1 : 2;
#pragma unroll
  for (int half = 0; half < nh; ++half) {
    u32 w[8];
#pragma unroll
    for (int i = 0; i < 8; ++i)
      w[i] = half ? cvtpk(s1[2 * i], s1[2 * i + 1])
                  : cvtpk(s0[2 * i], s0[2 * i + 1]);
#pragma unroll
    for (int kp = 0; kp < 2; ++kp) {
      const u32 w0 = w[4 * kp + 0], w1 = w[4 * kp + 1];
      const u32 w2 = w[4 * kp + 2], w3 = w[4 * kp + 3];
      const u32 t0 = hi ? w0 : w2, t1 = hi ? w1 : w3;
      const u32 x0 = (u32)__shfl_xor((int)t0, 32);
      const u32 x1 = (u32)__shfl_xor((int)t1, 32);
      union { u32 u[4]; s16x8 v; } bb;
      bb.u[0] = hi ? x0 : w0;
      bb.u[1] = hi ? x1 : w1;
      bb.u[2] = hi ? w2 : x0;
      bb.u[3] = hi ? w3 : x1;
      const int kc = half * 2 + kp;
      st.o0 = MFMA32(va0[kc], bb.v, st.o0, 0, 0, 0);
      st.o1 = MFMA32(va1[kc], bb.v, st.o1, 0, 0, 0);
    }
  }
}

__global__ __launch_bounds__(64, 2) void attn_kernel(
    const u16* __restrict__ Qg, const u16* __restrict__ Kg,
    const u16* __restrict__ Vt, u16* __restrict__ ctx) {
  const int lane = threadIdx.x & 63;
  const int la = lane & 31, hi = lane >> 5;
  const int bh = blockIdx.x & 31;
  const int qc = 63 - (blockIdx.x >> 5);  // heavy q-chunks dispatch first
  const int qs = qc * 32;
  const size_t baseK = (size_t)bh * 2048 * 64;
  const size_t baseV = (size_t)bh * 64 * 2048;
  const u16* Kb = Kg + baseK;
  const u16* Vb = Vt + baseV;

  A32 st;
#pragma unroll
  for (int c = 0; c < 4; ++c)
    st.q[c] = ld8(Qg + baseK + (size_t)(qs + la) * 64 + c * 16 + hi * 8);
#pragma unroll
  for (int r = 0; r < 16; ++r) { st.o0[r] = 0.f; st.o1[r] = 0.f; }
  st.m = -INFINITY;
  st.l = 0.f;

  const int nfull = qs >> 6;
  for (int kt = 0; kt < nfull; ++kt) body32<0>(st, kt * 64, Kb, Vb, la, hi);
  if (qs & 32) body32<1>(st, nfull * 64, Kb, Vb, la, hi);
  else         body32<2>(st, qs, Kb, Vb, la, hi);

  const int bb = bh >> 4, hh = bh & 15;
  const float inv = 1.0f / st.l;
  u16* crow = ctx + (size_t)(bb * 2048 + qs + la) * 1024 + hh * 64;
#pragma unroll
  for (int r = 0; r < 16; r += 2) {
    const int d = (r & 3) + 8 * (r >> 2) + 4 * hi;
    *(u32*)(crow + d) = cvtpk(st.o0[r] * inv, st.o0[r + 1] * inv);
    *(u32*)(crow + 32 + d) = cvtpk(st.o1[r] * inv, st.o1[r + 1] * inv);
  }
}

// ---------------------------------------------------------------------------
extern "C" void kernel_launch(void* const* d_in, const int* in_sizes, int n_in,
                              void* d_out, int out_size, void* d_ws,
                              size_t ws_size, hipStream_t stream) {
  const float* x  = (const float*)d_in[0];
  const float* wq = (const float*)d_in[1];
  const float* wk = (const float*)d_in[2];
  const float* wv = (const float*)d_in[3];
  const float* wo = (const float*)d_in[4];
  const float* bo = (const float*)d_in[5];
  const float* w1 = (const float*)d_in[6];
  const float* b1 = (const float*)d_in[7];
  const float* w2 = (const float*)d_in[8];
  const float* b2 = (const float*)d_in[9];
  const float* g1 = (const float*)d_in[10];
  const float* s1 = (const float*)d_in[11];
  const float* g2 = (const float*)d_in[12];
  const float* s2 = (const float*)d_in[13];
  float* out = (float*)d_out;

  const size_t MB = (size_t)1 << 20;
  char* p = (char*)d_ws;
  u16* hb    = (u16*)(p + 0 * MB);    // LN1 out (dead after QKV)
  u16* qbuf  = (u16*)(p + 8 * MB);    // q | k [32][2048][64], vt [32][64][2048]
  u16* ctxb  = (u16*)(p + 32 * MB);
  float* x2  = (float*)(p + 40 * MB); // residual fp32 (16MB)
  u16* h2b   = (u16*)(p + 56 * MB);   // LN2 out (8MB)
  u16* qkvw  = (u16*)(p + 64 * MB);   // [3072][1024] packed Wq/Wk/Wv^T (6MB)
  u16* wot   = (u16*)(p + 70 * MB);
  u16* w1t   = (u16*)(p + 72 * MB);
  u16* w2t   = (u16*)(p + 80 * MB);
  u16* gb    = (u16*)(p + 0 * MB);    // gelu out, aliases hb/qbuf (32MB)

  const dim3 blk(256);
  tconv_kernel<<<dim3(16, 16), blk, 0, stream>>>(wq, qkvw, 1024, 1024);
  tconv_kernel<<<dim3(16, 16), blk, 0, stream>>>(wk, qkvw + 1048576, 1024, 1024);
  tconv_kernel<<<dim3(16, 16), blk, 0, stream>>>(wv, qkvw + 2097152, 1024, 1024);
  tconv_kernel<<<dim3(16, 16), blk, 0, stream>>>(wo, wot, 1024, 1024);
  tconv_kernel<<<dim3(64, 16), blk, 0, stream>>>(w1, w1t, 1024, 4096);
  tconv_kernel<<<dim3(16, 64), blk, 0, stream>>>(w2, w2t, 4096, 1024);

  ln_kernel<<<4096, blk, 0, stream>>>(x, g1, s1, hb);
  gemm_kernel<0><<<dim3(24, 32), blk, 0, stream>>>(hb, qkvw, nullptr, nullptr,
                                                   qbuf, 4096, 3072, 1024);
  attn_kernel<<<dim3(2048), dim3(64), 0, stream>>>(
      qbuf, qbuf + 4194304, qbuf + 8388608, ctxb);
  gemm_kernel<1><<<dim3(8, 32), blk, 0, stream>>>(ctxb, wot, bo, x, x2, 4096,
                                                  1024, 1024);
  ln_kernel<<<4096, blk, 0, stream>>>(x2, g2, s2, h2b);
  gemm_kernel<2><<<dim3(32, 32), blk, 0, stream>>>(h2b, w1t, b1, nullptr, gb,
                                                   4096, 4096, 1024);
  gemm_kernel<1><<<dim3(8, 32), blk, 0, stream>>>(gb, w2t, b2, x2, out, 4096,
                                                  1024, 4096);
}

// Round 9
// 338.654 us; speedup vs baseline: 1.3013x; 1.0099x over previous
//
#include <hip/hip_runtime.h>

// TransformerBlock: B=2, S=2048, D=1024, H=16, dh=64, FFN=4096.
// Round 9: LDS XOR-swizzle on all GEMMs (conflict-free ds_read_b128),
// 256^2-tile 2-phase GEMM for FFN1, XCD-chunked block remap.

typedef __attribute__((ext_vector_type(8))) short s16x8;
typedef __attribute__((ext_vector_type(4))) float f32x4;
typedef __attribute__((ext_vector_type(16))) float f32x16;
typedef unsigned short u16;
typedef unsigned int u32;

#define DEV static __device__ __forceinline__
#define MFMA16 __builtin_amdgcn_mfma_f32_16x16x32_bf16
#define MFMA32 __builtin_amdgcn_mfma_f32_32x32x16_bf16
#define GLOAD_LDS16(gp, lp)                                         \
  __builtin_amdgcn_global_load_lds(                                 \
      (const __attribute__((address_space(1))) void*)(gp),          \
      (__attribute__((address_space(3))) void*)(lp), 16, 0, 0)

DEV u16 f2bf(float f) {
  union { float f; unsigned u; } c; c.f = f;
  unsigned u = c.u;
  u += 0x7fff + ((u >> 16) & 1);   // RNE
  return (u16)(u >> 16);
}

DEV u32 cvtpk(float lo, float hi) {  // packed f32x2 -> bf16x2 (RNE)
  u32 r;
  asm("v_cvt_pk_bf16_f32 %0, %1, %2" : "=v"(r) : "v"(lo), "v"(hi));
  return r;
}

DEV float gelu_tanh(float v) {
  const float c0 = 0.7978845608028654f;  // sqrt(2/pi)
  float u = c0 * (v + 0.044715f * v * v * v);
  return 0.5f * v * (1.0f + tanhf(u));
}

DEV s16x8 ld8(const u16* p) { return *(const s16x8*)p; }

// ---------- transpose + convert: W fp32 [K,N] -> Wt bf16 [N,K] -------------
__global__ __launch_bounds__(256) void tconv_kernel(
    const float* __restrict__ W, u16* __restrict__ Wt, int K, int N) {
  __shared__ u16 T[64][80];
  const int t = threadIdx.x;
  const int n0 = blockIdx.x * 64, k0 = blockIdx.y * 64;
  const int kr = t >> 4, nc = (t & 15) * 4;
#pragma unroll
  for (int p = 0; p < 4; ++p) {
    const int k = p * 16 + kr;
    float4 v = *(const float4*)(W + (size_t)(k0 + k) * N + n0 + nc);
    T[nc + 0][k] = f2bf(v.x);
    T[nc + 1][k] = f2bf(v.y);
    T[nc + 2][k] = f2bf(v.z);
    T[nc + 3][k] = f2bf(v.w);
  }
  __syncthreads();
  const int nr = t >> 2, kc = (t & 3) * 16;
  *(s16x8*)(Wt + (size_t)(n0 + nr) * K + k0 + kc) = *(const s16x8*)&T[nr][kc];
  *(s16x8*)(Wt + (size_t)(n0 + nr) * K + k0 + kc + 8) =
      *(const s16x8*)&T[nr][kc + 8];
}

// ---------------- LayerNorm: fp32 [rows,1024] -> bf16 [rows,1024] ----------
__global__ __launch_bounds__(256) void ln_kernel(
    const float* __restrict__ x, const float* __restrict__ g,
    const float* __restrict__ b, u16* __restrict__ out) {
  const int row = blockIdx.x;
  const int t = threadIdx.x;
  const float* xr = x + (size_t)row * 1024;
  float4 v = *(const float4*)(xr + t * 4);
  float s = v.x + v.y + v.z + v.w;
  float ss = v.x * v.x + v.y * v.y + v.z * v.z + v.w * v.w;
#pragma unroll
  for (int off = 1; off < 64; off <<= 1) {
    s += __shfl_xor(s, off);
    ss += __shfl_xor(ss, off);
  }
  __shared__ float sb[4], ssb[4];
  const int w = t >> 6;
  if ((t & 63) == 0) { sb[w] = s; ssb[w] = ss; }
  __syncthreads();
  s = sb[0] + sb[1] + sb[2] + sb[3];
  ss = ssb[0] + ssb[1] + ssb[2] + ssb[3];
  const float mean = s * (1.0f / 1024.0f);
  const float var = ss * (1.0f / 1024.0f) - mean * mean;
  const float rstd = rsqrtf(var + 1e-5f);
  const int c = t * 4;
  ushort4 o;
  o.x = f2bf(g[c + 0] * ((v.x - mean) * rstd) + b[c + 0]);
  o.y = f2bf(g[c + 1] * ((v.y - mean) * rstd) + b[c + 1]);
  o.z = f2bf(g[c + 2] * ((v.z - mean) * rstd) + b[c + 2]);
  o.w = f2bf(g[c + 3] * ((v.w - mean) * rstd) + b[c + 3]);
  *(ushort4*)(out + (size_t)row * 1024 + c) = o;
}

// ---- XOR swizzle (64B LDS rows, 16B slots): phys_slot = log_slot ^ sw(row),
// sw(row) = (row>>1)&3. Write side pre-swizzles the GLOBAL source col since
// global_load_lds writes linearly (16-row chunks per 1KB issue).
// ---------------- GEMM 128^2: C = A[M,K] @ Bt[N,K]^T -----------------------
DEV void gemm_stage(const u16* __restrict__ A, const u16* __restrict__ Bt,
                    int bm, int bn, int K, int kof, u16 (*Al)[32],
                    u16 (*Bl)[32], int w, int lane) {
  const int srow = lane >> 2;
  const int scol = ((lane & 3) ^ ((lane >> 3) & 3)) * 8;  // swizzled source
#pragma unroll
  for (int p = 0; p < 2; ++p) {
    const int r0 = (w * 2 + p) * 16;
    GLOAD_LDS16(A + (size_t)(bm + r0 + srow) * K + kof + scol, &Al[r0][0]);
    GLOAD_LDS16(Bt + (size_t)(bn + r0 + srow) * K + kof + scol, &Bl[r0][0]);
  }
}

DEV void gemm_step(const u16 (*Al)[32], const u16 (*Bl)[32],
                   f32x4 (&acc)[4][4], int wm, int wn, int lr, int lg) {
  const int cs = (lg ^ ((lr >> 1) & 3)) * 8;  // swizzled read col
  s16x8 af[4], bf[4];
#pragma unroll
  for (int i = 0; i < 4; ++i) {
    af[i] = *(const s16x8*)&Al[wm + i * 16 + lr][cs];
    bf[i] = *(const s16x8*)&Bl[wn + i * 16 + lr][cs];
  }
#pragma unroll
  for (int i = 0; i < 4; ++i)
#pragma unroll
    for (int j = 0; j < 4; ++j)
      acc[i][j] = MFMA16(af[i], bf[j], acc[i][j], 0, 0, 0);
}

template <int EPI>
__global__ __launch_bounds__(256) void gemm_kernel(
    const u16* __restrict__ A, const u16* __restrict__ Bt,
    const float* __restrict__ bias, const float* __restrict__ res,
    void* __restrict__ Cv, int M, int N, int K) {
  __shared__ __align__(16) u16 Al[2][128][32];
  __shared__ __align__(16) u16 Bl[2][128][32];
  const int t = threadIdx.x;
  const int lane = t & 63, w = t >> 6;
  const int wm = (w >> 1) * 64, wn = (w & 1) * 64;
  // XCD-chunked bijective remap (all grids have nwg % 8 == 0)
  int bid = blockIdx.y * gridDim.x + blockIdx.x;
  const int q8 = (gridDim.x * gridDim.y) >> 3;
  bid = (bid & 7) * q8 + (bid >> 3);
  const int bm = (bid / gridDim.x) * 128, bn = (bid % gridDim.x) * 128;
  const int lr = lane & 15, lg = lane >> 4;
  f32x4 acc[4][4] = {};
  const int nkt = K >> 5;

  gemm_stage(A, Bt, bm, bn, K, 0, Al[0], Bl[0], w, lane);
  __syncthreads();
  for (int kt = 0; kt < nkt - 1; ++kt) {
    const int cur = kt & 1;
    gemm_stage(A, Bt, bm, bn, K, (kt + 1) << 5, Al[cur ^ 1], Bl[cur ^ 1], w,
               lane);
    gemm_step(Al[cur], Bl[cur], acc, wm, wn, lr, lg);
    __syncthreads();
  }
  gemm_step(Al[(nkt - 1) & 1], Bl[(nkt - 1) & 1], acc, wm, wn, lr, lg);

#pragma unroll
  for (int i = 0; i < 4; ++i) {
    const int row = bm + wm + i * 16 + lg * 4;  // + e
#pragma unroll
    for (int j = 0; j < 4; ++j) {
      const int col = bn + wn + j * 16 + lr;
      if (EPI == 0) {
        const int bb = row >> 11, sloc = row & 2047;
        const int which = col >> 10, n = col & 1023;
        const int hh = n >> 6, dd = n & 63;
        u16* qbuf = (u16*)Cv;
        if (which == 2) {  // V transposed [bh][64][2048]
          ushort4 o;
          o.x = f2bf(acc[i][j][0]); o.y = f2bf(acc[i][j][1]);
          o.z = f2bf(acc[i][j][2]); o.w = f2bf(acc[i][j][3]);
          *(ushort4*)(qbuf + 8388608 +
                      (size_t)((bb * 16 + hh) * 64 + dd) * 2048 + sloc) = o;
        } else {
          // q pre-scaled by (1/8)*log2(e) so attention runs in exp2 space
          const float sc = (which == 0) ? 0.18033688011112042f : 1.0f;
          u16* dst = qbuf + (size_t)which * 4194304 +
                     ((size_t)(bb * 16 + hh) * 2048 + sloc) * 64 + dd;
#pragma unroll
          for (int e = 0; e < 4; ++e) dst[(size_t)e * 64] = f2bf(acc[i][j][e] * sc);
        }
      } else if (EPI == 1) {
        float* C = (float*)Cv;
        const float bs = bias[col];
#pragma unroll
        for (int e = 0; e < 4; ++e)
          C[(size_t)(row + e) * N + col] =
              acc[i][j][e] + bs + res[(size_t)(row + e) * N + col];
      } else {
        u16* C = (u16*)Cv;
        const float bs = bias[col];
#pragma unroll
        for (int e = 0; e < 4; ++e)
          C[(size_t)(row + e) * N + col] = f2bf(gelu_tanh(acc[i][j][e] + bs));
      }
    }
  }
}

// ---------------- GEMM 256^2: 8 waves, wave-tile 128x64, BK=32 -------------
DEV void g256_stage(const u16* __restrict__ A, const u16* __restrict__ Bt,
                    int bm, int bn, int K, int kof, u16 (*Al)[32],
                    u16 (*Bl)[32], int w, int lane) {
  const int srow = lane >> 2;
  const int scol = ((lane & 3) ^ ((lane >> 3) & 3)) * 8;
#pragma unroll
  for (int c = 0; c < 2; ++c) {
    const int r0 = (w << 5) + (c << 4);
    GLOAD_LDS16(A + (size_t)(bm + r0 + srow) * K + kof + scol, &Al[r0][0]);
    GLOAD_LDS16(Bt + (size_t)(bn + r0 + srow) * K + kof + scol, &Bl[r0][0]);
  }
}

DEV void g256_step(const u16 (*Al)[32], const u16 (*Bl)[32],
                   f32x4 (&acc)[8][4], int wm, int wn, int lr, int lg) {
  const int cs = (lg ^ ((lr >> 1) & 3)) * 8;
  s16x8 af[8], bf[4];
#pragma unroll
  for (int i = 0; i < 8; ++i)
    af[i] = *(const s16x8*)&Al[wm + i * 16 + lr][cs];
#pragma unroll
  for (int j = 0; j < 4; ++j)
    bf[j] = *(const s16x8*)&Bl[wn + j * 16 + lr][cs];
#pragma unroll
  for (int i = 0; i < 8; ++i)
#pragma unroll
    for (int j = 0; j < 4; ++j)
      acc[i][j] = MFMA16(af[i], bf[j], acc[i][j], 0, 0, 0);
}

template <int EPI>
__global__ __launch_bounds__(512, 2) void gemm256_kernel(
    const u16* __restrict__ A, const u16* __restrict__ Bt,
    const float* __restrict__ bias, const float* __restrict__ res,
    void* __restrict__ Cv, int M, int N, int K) {
  __shared__ __align__(16) u16 Al[2][256][32];
  __shared__ __align__(16) u16 Bl[2][256][32];
  const int t = threadIdx.x;
  const int lane = t & 63, w = t >> 6;           // 8 waves
  const int wm = (w >> 2) << 7;                  // 0 / 128
  const int wn = (w & 3) << 6;                   // 0/64/128/192
  int bid = blockIdx.y * gridDim.x + blockIdx.x;
  const int q8 = (gridDim.x * gridDim.y) >> 3;
  bid = (bid & 7) * q8 + (bid >> 3);
  const int bm = (bid / gridDim.x) << 8, bn = (bid % gridDim.x) << 8;
  const int lr = lane & 15, lg = lane >> 4;
  f32x4 acc[8][4] = {};
  const int nkt = K >> 5;

  g256_stage(A, Bt, bm, bn, K, 0, Al[0], Bl[0], w, lane);
  __syncthreads();
  for (int kt = 0; kt < nkt - 1; ++kt) {
    const int cur = kt & 1;
    g256_stage(A, Bt, bm, bn, K, (kt + 1) << 5, Al[cur ^ 1], Bl[cur ^ 1], w,
               lane);
    g256_step(Al[cur], Bl[cur], acc, wm, wn, lr, lg);
    __syncthreads();
  }
  g256_step(Al[(nkt - 1) & 1], Bl[(nkt - 1) & 1], acc, wm, wn, lr, lg);

#pragma unroll
  for (int i = 0; i < 8; ++i) {
    const int row = bm + wm + i * 16 + lg * 4;  // + e
#pragma unroll
    for (int j = 0; j < 4; ++j) {
      const int col = bn + wn + j * 16 + lr;
      if (EPI == 1) {
        float* C = (float*)Cv;
        const float bs = bias[col];
#pragma unroll
        for (int e = 0; e < 4; ++e)
          C[(size_t)(row + e) * N + col] =
              acc[i][j][e] + bs + res[(size_t)(row + e) * N + col];
      } else {
        u16* C = (u16*)Cv;
        const float bs = bias[col];
#pragma unroll
        for (int e = 0; e < 4; ++e)
          C[(size_t)(row + e) * N + col] = f2bf(gelu_tanh(acc[i][j][e] + bs));
      }
    }
  }
}

// ---------------- Flash attention: 32x32 swapped, zero-LDS (round 8) -------
DEV float vmax16(const f32x16& v) {
  float a = fmaxf(v[0], v[1]), b = fmaxf(v[2], v[3]);
  float c = fmaxf(v[4], v[5]), d = fmaxf(v[6], v[7]);
  float e = fmaxf(v[8], v[9]), f = fmaxf(v[10], v[11]);
  float g = fmaxf(v[12], v[13]), h = fmaxf(v[14], v[15]);
  a = fmaxf(a, b); c = fmaxf(c, d); e = fmaxf(e, f); g = fmaxf(g, h);
  return fmaxf(fmaxf(a, c), fmaxf(e, g));
}
DEV float vsum16(const f32x16& v) {
  float a = v[0] + v[1], b = v[2] + v[3];
  float c = v[4] + v[5], d = v[6] + v[7];
  float e = v[8] + v[9], f = v[10] + v[11];
  float g = v[12] + v[13], h = v[14] + v[15];
  a += b; c += d; e += f; g += h;
  return (a + c) + (e + g);
}

struct A32 {
  s16x8 q[4];
  f32x16 o0, o1;
  float m, l;
};

template <int MODE>  // 0 interior, 1 full-diag, 2 half-tile
DEV void body32(A32& st, int k0, const u16* Kb, const u16* Vb, int la,
                int hi) {
  s16x8 ka0[4], ka1[4];
#pragma unroll
  for (int c = 0; c < 4; ++c)
    ka0[c] = ld8(Kb + (size_t)(k0 + la) * 64 + c * 16 + hi * 8);
  if (MODE != 2)
#pragma unroll
    for (int c = 0; c < 4; ++c)
      ka1[c] = ld8(Kb + (size_t)(k0 + 32 + la) * 64 + c * 16 + hi * 8);
  f32x16 s0, s1;
#pragma unroll
  for (int r = 0; r < 16; ++r) { s0[r] = 0.f; s1[r] = 0.f; }
#pragma unroll
  for (int c = 0; c < 4; ++c) s0 = MFMA32(ka0[c], st.q[c], s0, 0, 0, 0);
  if (MODE != 2)
#pragma unroll
    for (int c = 0; c < 4; ++c) s1 = MFMA32(ka1[c], st.q[c], s1, 0, 0, 0);
  const int nkc = (MODE == 2) ? 2 : 4;
  s16x8 va0[4], va1[4];
#pragma unroll
  for (int kc = 0; kc < 4; ++kc)
    if (kc < nkc) {
      va0[kc] = ld8(Vb + (size_t)la * 2048 + k0 + kc * 16 + hi * 8);
      va1[kc] = ld8(Vb + (size_t)(32 + la) * 2048 + k0 + kc * 16 + hi * 8);
    }
  if (MODE == 1) {
#pragma unroll
    for (int r = 0; r < 16; ++r) {
      const int kl = (r & 3) + 8 * (r >> 2) + 4 * hi;
      if (kl > la) s1[r] = -INFINITY;
    }
  }
  if (MODE == 2) {
#pragma unroll
    for (int r = 0; r < 16; ++r) {
      const int kl = (r & 3) + 8 * (r >> 2) + 4 * hi;
      if (kl > la) s0[r] = -INFINITY;
    }
  }
  float mt = vmax16(s0);
  if (MODE != 2) mt = fmaxf(mt, vmax16(s1));
  mt = fmaxf(mt, __shfl_xor(mt, 32));
  const float mn = fmaxf(st.m, mt);
  const float sf = exp2f(st.m - mn);
#pragma unroll
  for (int r = 0; r < 16; ++r) s0[r] = exp2f(s0[r] - mn);
  if (MODE != 2)
#pragma unroll
    for (int r = 0; r < 16; ++r) s1[r] = exp2f(s1[r] - mn);
  float rs = vsum16(s0);
  if (MODE != 2) rs += vsum16(s1);
  rs += __shfl_xor(rs, 32);
  st.l = st.l * sf + rs;
  st.m = mn;
#pragma unroll
  for (int r = 0; r < 16; ++r) { st.o0[r] *= sf; st.o1[r] *= sf; }
  const int nh = (MODE == 2) ? 1 : 2;
#pragma unroll
  for (int half = 0; half < nh; ++half) {
    u32 w[8];
#pragma unroll
    for (int i = 0; i < 8; ++i)
      w[i] = half ? cvtpk(s1[2 * i], s1[2 * i + 1])
                  : cvtpk(s0[2 * i], s0[2 * i + 1]);
#pragma unroll
    for (int kp = 0; kp < 2; ++kp) {
      const u32 w0 = w[4 * kp + 0], w1 = w[4 * kp + 1];
      const u32 w2 = w[4 * kp + 2], w3 = w[4 * kp + 3];
      const u32 t0 = hi ? w0 : w2, t1 = hi ? w1 : w3;
      const u32 x0 = (u32)__shfl_xor((int)t0, 32);
      const u32 x1 = (u32)__shfl_xor((int)t1, 32);
      union { u32 u[4]; s16x8 v; } bb;
      bb.u[0] = hi ? x0 : w0;
      bb.u[1] = hi ? x1 : w1;
      bb.u[2] = hi ? w2 : x0;
      bb.u[3] = hi ? w3 : x1;
      const int kc = half * 2 + kp;
      st.o0 = MFMA32(va0[kc], bb.v, st.o0, 0, 0, 0);
      st.o1 = MFMA32(va1[kc], bb.v, st.o1, 0, 0, 0);
    }
  }
}

__global__ __launch_bounds__(64, 2) void attn_kernel(
    const u16* __restrict__ Qg, const u16* __restrict__ Kg,
    const u16* __restrict__ Vt, u16* __restrict__ ctx) {
  const int lane = threadIdx.x & 63;
  const int la = lane & 31, hi = lane >> 5;
  const int bh = blockIdx.x & 31;
  const int qc = 63 - (blockIdx.x >> 5);  // heavy q-chunks dispatch first
  const int qs = qc * 32;
  const size_t baseK = (size_t)bh * 2048 * 64;
  const size_t baseV = (size_t)bh * 64 * 2048;
  const u16* Kb = Kg + baseK;
  const u16* Vb = Vt + baseV;

  A32 st;
#pragma unroll
  for (int c = 0; c < 4; ++c)
    st.q[c] = ld8(Qg + baseK + (size_t)(qs + la) * 64 + c * 16 + hi * 8);
#pragma unroll
  for (int r = 0; r < 16; ++r) { st.o0[r] = 0.f; st.o1[r] = 0.f; }
  st.m = -INFINITY;
  st.l = 0.f;

  const int nfull = qs >> 6;
  for (int kt = 0; kt < nfull; ++kt) body32<0>(st, kt * 64, Kb, Vb, la, hi);
  if (qs & 32) body32<1>(st, nfull * 64, Kb, Vb, la, hi);
  else         body32<2>(st, qs, Kb, Vb, la, hi);

  const int bb = bh >> 4, hh = bh & 15;
  const float inv = 1.0f / st.l;
  u16* crow = ctx + (size_t)(bb * 2048 + qs + la) * 1024 + hh * 64;
#pragma unroll
  for (int r = 0; r < 16; r += 2) {
    const int d = (r & 3) + 8 * (r >> 2) + 4 * hi;
    *(u32*)(crow + d) = cvtpk(st.o0[r] * inv, st.o0[r + 1] * inv);
    *(u32*)(crow + 32 + d) = cvtpk(st.o1[r] * inv, st.o1[r + 1] * inv);
  }
}

// ---------------------------------------------------------------------------
extern "C" void kernel_launch(void* const* d_in, const int* in_sizes, int n_in,
                              void* d_out, int out_size, void* d_ws,
                              size_t ws_size, hipStream_t stream) {
  const float* x  = (const float*)d_in[0];
  const float* wq = (const float*)d_in[1];
  const float* wk = (const float*)d_in[2];
  const float* wv = (const float*)d_in[3];
  const float* wo = (const float*)d_in[4];
  const float* bo = (const float*)d_in[5];
  const float* w1 = (const float*)d_in[6];
  const float* b1 = (const float*)d_in[7];
  const float* w2 = (const float*)d_in[8];
  const float* b2 = (const float*)d_in[9];
  const float* g1 = (const float*)d_in[10];
  const float* s1 = (const float*)d_in[11];
  const float* g2 = (const float*)d_in[12];
  const float* s2 = (const float*)d_in[13];
  float* out = (float*)d_out;

  const size_t MB = (size_t)1 << 20;
  char* p = (char*)d_ws;
  u16* hb    = (u16*)(p + 0 * MB);    // LN1 out (dead after QKV)
  u16* qbuf  = (u16*)(p + 8 * MB);    // q | k [32][2048][64], vt [32][64][2048]
  u16* ctxb  = (u16*)(p + 32 * MB);
  float* x2  = (float*)(p + 40 * MB); // residual fp32 (16MB)
  u16* h2b   = (u16*)(p + 56 * MB);   // LN2 out (8MB)
  u16* qkvw  = (u16*)(p + 64 * MB);   // [3072][1024] packed Wq/Wk/Wv^T (6MB)
  u16* wot   = (u16*)(p + 70 * MB);
  u16* w1t   = (u16*)(p + 72 * MB);
  u16* w2t   = (u16*)(p + 80 * MB);
  u16* gb    = (u16*)(p + 0 * MB);    // gelu out, aliases hb/qbuf (32MB)

  const dim3 blk(256);
  tconv_kernel<<<dim3(16, 16), blk, 0, stream>>>(wq, qkvw, 1024, 1024);
  tconv_kernel<<<dim3(16, 16), blk, 0, stream>>>(wk, qkvw + 1048576, 1024, 1024);
  tconv_kernel<<<dim3(16, 16), blk, 0, stream>>>(wv, qkvw + 2097152, 1024, 1024);
  tconv_kernel<<<dim3(16, 16), blk, 0, stream>>>(wo, wot, 1024, 1024);
  tconv_kernel<<<dim3(64, 16), blk, 0, stream>>>(w1, w1t, 1024, 4096);
  tconv_kernel<<<dim3(16, 64), blk, 0, stream>>>(w2, w2t, 4096, 1024);

  ln_kernel<<<4096, blk, 0, stream>>>(x, g1, s1, hb);
  gemm_kernel<0><<<dim3(24, 32), blk, 0, stream>>>(hb, qkvw, nullptr, nullptr,
                                                   qbuf, 4096, 3072, 1024);
  attn_kernel<<<dim3(2048), dim3(64), 0, stream>>>(
      qbuf, qbuf + 4194304, qbuf + 8388608, ctxb);
  gemm_kernel<1><<<dim3(8, 32), blk, 0, stream>>>(ctxb, wot, bo, x, x2, 4096,
                                                  1024, 1024);
  ln_kernel<<<4096, blk, 0, stream>>>(x2, g2, s2, h2b);
  gemm256_kernel<2><<<dim3(16, 16), dim3(512), 0, stream>>>(
      h2b, w1t, b1, nullptr, gb, 4096, 4096, 1024);
  gemm_kernel<1><<<dim3(8, 32), blk, 0, stream>>>(gb, w2t, b2, x2, out, 4096,
                                                  1024, 4096);
}

// Round 10
// 307.264 us; speedup vs baseline: 1.4342x; 1.1022x over previous
//
#include <hip/hip_runtime.h>

// TransformerBlock: B=2, S=2048, D=1024, H=16, dh=64, FFN=4096.
// Round 10: 64x64-tile GEMM for the 256-block-starved N=1024 GEMMs
// (proj, FFN2) -> 1024 blocks, 4/CU. Swizzled LDS everywhere (round 9).

typedef __attribute__((ext_vector_type(8))) short s16x8;
typedef __attribute__((ext_vector_type(4))) float f32x4;
typedef __attribute__((ext_vector_type(16))) float f32x16;
typedef unsigned short u16;
typedef unsigned int u32;

#define DEV static __device__ __forceinline__
#define MFMA16 __builtin_amdgcn_mfma_f32_16x16x32_bf16
#define MFMA32 __builtin_amdgcn_mfma_f32_32x32x16_bf16
#define GLOAD_LDS16(gp, lp)                                         \
  __builtin_amdgcn_global_load_lds(                                 \
      (const __attribute__((address_space(1))) void*)(gp),          \
      (__attribute__((address_space(3))) void*)(lp), 16, 0, 0)

DEV u16 f2bf(float f) {
  union { float f; unsigned u; } c; c.f = f;
  unsigned u = c.u;
  u += 0x7fff + ((u >> 16) & 1);   // RNE
  return (u16)(u >> 16);
}

DEV u32 cvtpk(float lo, float hi) {  // packed f32x2 -> bf16x2 (RNE)
  u32 r;
  asm("v_cvt_pk_bf16_f32 %0, %1, %2" : "=v"(r) : "v"(lo), "v"(hi));
  return r;
}

DEV float gelu_tanh(float v) {
  const float c0 = 0.7978845608028654f;  // sqrt(2/pi)
  float u = c0 * (v + 0.044715f * v * v * v);
  return 0.5f * v * (1.0f + tanhf(u));
}

DEV s16x8 ld8(const u16* p) { return *(const s16x8*)p; }

// ---------- transpose + convert: W fp32 [K,N] -> Wt bf16 [N,K] -------------
__global__ __launch_bounds__(256) void tconv_kernel(
    const float* __restrict__ W, u16* __restrict__ Wt, int K, int N) {
  __shared__ u16 T[64][80];
  const int t = threadIdx.x;
  const int n0 = blockIdx.x * 64, k0 = blockIdx.y * 64;
  const int kr = t >> 4, nc = (t & 15) * 4;
#pragma unroll
  for (int p = 0; p < 4; ++p) {
    const int k = p * 16 + kr;
    float4 v = *(const float4*)(W + (size_t)(k0 + k) * N + n0 + nc);
    T[nc + 0][k] = f2bf(v.x);
    T[nc + 1][k] = f2bf(v.y);
    T[nc + 2][k] = f2bf(v.z);
    T[nc + 3][k] = f2bf(v.w);
  }
  __syncthreads();
  const int nr = t >> 2, kc = (t & 3) * 16;
  *(s16x8*)(Wt + (size_t)(n0 + nr) * K + k0 + kc) = *(const s16x8*)&T[nr][kc];
  *(s16x8*)(Wt + (size_t)(n0 + nr) * K + k0 + kc + 8) =
      *(const s16x8*)&T[nr][kc + 8];
}

// ---------------- LayerNorm: fp32 [rows,1024] -> bf16 [rows,1024] ----------
__global__ __launch_bounds__(256) void ln_kernel(
    const float* __restrict__ x, const float* __restrict__ g,
    const float* __restrict__ b, u16* __restrict__ out) {
  const int row = blockIdx.x;
  const int t = threadIdx.x;
  const float* xr = x + (size_t)row * 1024;
  float4 v = *(const float4*)(xr + t * 4);
  float s = v.x + v.y + v.z + v.w;
  float ss = v.x * v.x + v.y * v.y + v.z * v.z + v.w * v.w;
#pragma unroll
  for (int off = 1; off < 64; off <<= 1) {
    s += __shfl_xor(s, off);
    ss += __shfl_xor(ss, off);
  }
  __shared__ float sb[4], ssb[4];
  const int w = t >> 6;
  if ((t & 63) == 0) { sb[w] = s; ssb[w] = ss; }
  __syncthreads();
  s = sb[0] + sb[1] + sb[2] + sb[3];
  ss = ssb[0] + ssb[1] + ssb[2] + ssb[3];
  const float mean = s * (1.0f / 1024.0f);
  const float var = ss * (1.0f / 1024.0f) - mean * mean;
  const float rstd = rsqrtf(var + 1e-5f);
  const int c = t * 4;
  ushort4 o;
  o.x = f2bf(g[c + 0] * ((v.x - mean) * rstd) + b[c + 0]);
  o.y = f2bf(g[c + 1] * ((v.y - mean) * rstd) + b[c + 1]);
  o.z = f2bf(g[c + 2] * ((v.z - mean) * rstd) + b[c + 2]);
  o.w = f2bf(g[c + 3] * ((v.w - mean) * rstd) + b[c + 3]);
  *(ushort4*)(out + (size_t)row * 1024 + c) = o;
}

// ---- XOR swizzle (64B LDS rows, 16B slots): phys_slot = log_slot ^ sw(row),
// sw(row) = (row>>1)&3. Write side pre-swizzles the GLOBAL source col since
// global_load_lds writes linearly (16-row chunks per 1KB issue).
// ---------------- GEMM 128^2: C = A[M,K] @ Bt[N,K]^T -----------------------
DEV void gemm_stage(const u16* __restrict__ A, const u16* __restrict__ Bt,
                    int bm, int bn, int K, int kof, u16 (*Al)[32],
                    u16 (*Bl)[32], int w, int lane) {
  const int srow = lane >> 2;
  const int scol = ((lane & 3) ^ ((lane >> 3) & 3)) * 8;  // swizzled source
#pragma unroll
  for (int p = 0; p < 2; ++p) {
    const int r0 = (w * 2 + p) * 16;
    GLOAD_LDS16(A + (size_t)(bm + r0 + srow) * K + kof + scol, &Al[r0][0]);
    GLOAD_LDS16(Bt + (size_t)(bn + r0 + srow) * K + kof + scol, &Bl[r0][0]);
  }
}

DEV void gemm_step(const u16 (*Al)[32], const u16 (*Bl)[32],
                   f32x4 (&acc)[4][4], int wm, int wn, int lr, int lg) {
  const int cs = (lg ^ ((lr >> 1) & 3)) * 8;  // swizzled read col
  s16x8 af[4], bf[4];
#pragma unroll
  for (int i = 0; i < 4; ++i) {
    af[i] = *(const s16x8*)&Al[wm + i * 16 + lr][cs];
    bf[i] = *(const s16x8*)&Bl[wn + i * 16 + lr][cs];
  }
#pragma unroll
  for (int i = 0; i < 4; ++i)
#pragma unroll
    for (int j = 0; j < 4; ++j)
      acc[i][j] = MFMA16(af[i], bf[j], acc[i][j], 0, 0, 0);
}

template <int EPI>
__global__ __launch_bounds__(256) void gemm_kernel(
    const u16* __restrict__ A, const u16* __restrict__ Bt,
    const float* __restrict__ bias, const float* __restrict__ res,
    void* __restrict__ Cv, int M, int N, int K) {
  __shared__ __align__(16) u16 Al[2][128][32];
  __shared__ __align__(16) u16 Bl[2][128][32];
  const int t = threadIdx.x;
  const int lane = t & 63, w = t >> 6;
  const int wm = (w >> 1) * 64, wn = (w & 1) * 64;
  int bid = blockIdx.y * gridDim.x + blockIdx.x;
  const int q8 = (gridDim.x * gridDim.y) >> 3;
  bid = (bid & 7) * q8 + (bid >> 3);
  const int bm = (bid / gridDim.x) * 128, bn = (bid % gridDim.x) * 128;
  const int lr = lane & 15, lg = lane >> 4;
  f32x4 acc[4][4] = {};
  const int nkt = K >> 5;

  gemm_stage(A, Bt, bm, bn, K, 0, Al[0], Bl[0], w, lane);
  __syncthreads();
  for (int kt = 0; kt < nkt - 1; ++kt) {
    const int cur = kt & 1;
    gemm_stage(A, Bt, bm, bn, K, (kt + 1) << 5, Al[cur ^ 1], Bl[cur ^ 1], w,
               lane);
    gemm_step(Al[cur], Bl[cur], acc, wm, wn, lr, lg);
    __syncthreads();
  }
  gemm_step(Al[(nkt - 1) & 1], Bl[(nkt - 1) & 1], acc, wm, wn, lr, lg);

#pragma unroll
  for (int i = 0; i < 4; ++i) {
    const int row = bm + wm + i * 16 + lg * 4;  // + e
#pragma unroll
    for (int j = 0; j < 4; ++j) {
      const int col = bn + wn + j * 16 + lr;
      if (EPI == 0) {
        const int bb = row >> 11, sloc = row & 2047;
        const int which = col >> 10, n = col & 1023;
        const int hh = n >> 6, dd = n & 63;
        u16* qbuf = (u16*)Cv;
        if (which == 2) {  // V transposed [bh][64][2048]
          ushort4 o;
          o.x = f2bf(acc[i][j][0]); o.y = f2bf(acc[i][j][1]);
          o.z = f2bf(acc[i][j][2]); o.w = f2bf(acc[i][j][3]);
          *(ushort4*)(qbuf + 8388608 +
                      (size_t)((bb * 16 + hh) * 64 + dd) * 2048 + sloc) = o;
        } else {
          // q pre-scaled by (1/8)*log2(e) so attention runs in exp2 space
          const float sc = (which == 0) ? 0.18033688011112042f : 1.0f;
          u16* dst = qbuf + (size_t)which * 4194304 +
                     ((size_t)(bb * 16 + hh) * 2048 + sloc) * 64 + dd;
#pragma unroll
          for (int e = 0; e < 4; ++e) dst[(size_t)e * 64] = f2bf(acc[i][j][e] * sc);
        }
      } else if (EPI == 1) {
        float* C = (float*)Cv;
        const float bs = bias[col];
#pragma unroll
        for (int e = 0; e < 4; ++e)
          C[(size_t)(row + e) * N + col] =
              acc[i][j][e] + bs + res[(size_t)(row + e) * N + col];
      } else {
        u16* C = (u16*)Cv;
        const float bs = bias[col];
#pragma unroll
        for (int e = 0; e < 4; ++e)
          C[(size_t)(row + e) * N + col] = f2bf(gelu_tanh(acc[i][j][e] + bs));
      }
    }
  }
}

// ---------------- GEMM 64^2: 4 waves, wave-tile 32x32, 4 blocks/CU ---------
DEV void g64_stage(const u16* __restrict__ A, const u16* __restrict__ Bt,
                   int bm, int bn, int K, int kof, u16 (*Al)[32],
                   u16 (*Bl)[32], int w, int lane) {
  const int srow = lane >> 2;
  const int scol = ((lane & 3) ^ ((lane >> 3) & 3)) * 8;
  const int r0 = w << 4;
  GLOAD_LDS16(A + (size_t)(bm + r0 + srow) * K + kof + scol, &Al[r0][0]);
  GLOAD_LDS16(Bt + (size_t)(bn + r0 + srow) * K + kof + scol, &Bl[r0][0]);
}

DEV void g64_step(const u16 (*Al)[32], const u16 (*Bl)[32],
                  f32x4 (&acc)[2][2], int wm, int wn, int lr, int lg) {
  const int cs = (lg ^ ((lr >> 1) & 3)) * 8;
  s16x8 af[2], bf[2];
#pragma unroll
  for (int i = 0; i < 2; ++i) {
    af[i] = *(const s16x8*)&Al[wm + i * 16 + lr][cs];
    bf[i] = *(const s16x8*)&Bl[wn + i * 16 + lr][cs];
  }
#pragma unroll
  for (int i = 0; i < 2; ++i)
#pragma unroll
    for (int j = 0; j < 2; ++j)
      acc[i][j] = MFMA16(af[i], bf[j], acc[i][j], 0, 0, 0);
}

template <int EPI>
__global__ __launch_bounds__(256) void gemm64_kernel(
    const u16* __restrict__ A, const u16* __restrict__ Bt,
    const float* __restrict__ bias, const float* __restrict__ res,
    void* __restrict__ Cv, int M, int N, int K) {
  __shared__ __align__(16) u16 Al[2][64][32];
  __shared__ __align__(16) u16 Bl[2][64][32];
  const int t = threadIdx.x;
  const int lane = t & 63, w = t >> 6;
  const int wm = (w >> 1) * 32, wn = (w & 1) * 32;
  int bid = blockIdx.y * gridDim.x + blockIdx.x;
  const int q8 = (gridDim.x * gridDim.y) >> 3;
  bid = (bid & 7) * q8 + (bid >> 3);
  const int bm = (bid / gridDim.x) * 64, bn = (bid % gridDim.x) * 64;
  const int lr = lane & 15, lg = lane >> 4;
  f32x4 acc[2][2] = {};
  const int nkt = K >> 5;

  g64_stage(A, Bt, bm, bn, K, 0, Al[0], Bl[0], w, lane);
  __syncthreads();
  for (int kt = 0; kt < nkt - 1; ++kt) {
    const int cur = kt & 1;
    g64_stage(A, Bt, bm, bn, K, (kt + 1) << 5, Al[cur ^ 1], Bl[cur ^ 1], w,
              lane);
    g64_step(Al[cur], Bl[cur], acc, wm, wn, lr, lg);
    __syncthreads();
  }
  g64_step(Al[(nkt - 1) & 1], Bl[(nkt - 1) & 1], acc, wm, wn, lr, lg);

#pragma unroll
  for (int i = 0; i < 2; ++i) {
    const int row = bm + wm + i * 16 + lg * 4;  // + e
#pragma unroll
    for (int j = 0; j < 2; ++j) {
      const int col = bn + wn + j * 16 + lr;
      if (EPI == 1) {
        float* C = (float*)Cv;
        const float bs = bias[col];
#pragma unroll
        for (int e = 0; e < 4; ++e)
          C[(size_t)(row + e) * N + col] =
              acc[i][j][e] + bs + res[(size_t)(row + e) * N + col];
      } else {
        u16* C = (u16*)Cv;
        const float bs = bias[col];
#pragma unroll
        for (int e = 0; e < 4; ++e)
          C[(size_t)(row + e) * N + col] = f2bf(gelu_tanh(acc[i][j][e] + bs));
      }
    }
  }
}

// ---------------- GEMM 256^2: 8 waves, wave-tile 128x64, BK=32 -------------
DEV void g256_stage(const u16* __restrict__ A, const u16* __restrict__ Bt,
                    int bm, int bn, int K, int kof, u16 (*Al)[32],
                    u16 (*Bl)[32], int w, int lane) {
  const int srow = lane >> 2;
  const int scol = ((lane & 3) ^ ((lane >> 3) & 3)) * 8;
#pragma unroll
  for (int c = 0; c < 2; ++c) {
    const int r0 = (w << 5) + (c << 4);
    GLOAD_LDS16(A + (size_t)(bm + r0 + srow) * K + kof + scol, &Al[r0][0]);
    GLOAD_LDS16(Bt + (size_t)(bn + r0 + srow) * K + kof + scol, &Bl[r0][0]);
  }
}

DEV void g256_step(const u16 (*Al)[32], const u16 (*Bl)[32],
                   f32x4 (&acc)[8][4], int wm, int wn, int lr, int lg) {
  const int cs = (lg ^ ((lr >> 1) & 3)) * 8;
  s16x8 af[8], bf[4];
#pragma unroll
  for (int i = 0; i < 8; ++i)
    af[i] = *(const s16x8*)&Al[wm + i * 16 + lr][cs];
#pragma unroll
  for (int j = 0; j < 4; ++j)
    bf[j] = *(const s16x8*)&Bl[wn + j * 16 + lr][cs];
#pragma unroll
  for (int i = 0; i < 8; ++i)
#pragma unroll
    for (int j = 0; j < 4; ++j)
      acc[i][j] = MFMA16(af[i], bf[j], acc[i][j], 0, 0, 0);
}

template <int EPI>
__global__ __launch_bounds__(512, 2) void gemm256_kernel(
    const u16* __restrict__ A, const u16* __restrict__ Bt,
    const float* __restrict__ bias, const float* __restrict__ res,
    void* __restrict__ Cv, int M, int N, int K) {
  __shared__ __align__(16) u16 Al[2][256][32];
  __shared__ __align__(16) u16 Bl[2][256][32];
  const int t = threadIdx.x;
  const int lane = t & 63, w = t >> 6;           // 8 waves
  const int wm = (w >> 2) << 7;                  // 0 / 128
  const int wn = (w & 3) << 6;                   // 0/64/128/192
  int bid = blockIdx.y * gridDim.x + blockIdx.x;
  const int q8 = (gridDim.x * gridDim.y) >> 3;
  bid = (bid & 7) * q8 + (bid >> 3);
  const int bm = (bid / gridDim.x) << 8, bn = (bid % gridDim.x) << 8;
  const int lr = lane & 15, lg = lane >> 4;
  f32x4 acc[8][4] = {};
  const int nkt = K >> 5;

  g256_stage(A, Bt, bm, bn, K, 0, Al[0], Bl[0], w, lane);
  __syncthreads();
  for (int kt = 0; kt < nkt - 1; ++kt) {
    const int cur = kt & 1;
    g256_stage(A, Bt, bm, bn, K, (kt + 1) << 5, Al[cur ^ 1], Bl[cur ^ 1], w,
               lane);
    g256_step(Al[cur], Bl[cur], acc, wm, wn, lr, lg);
    __syncthreads();
  }
  g256_step(Al[(nkt - 1) & 1], Bl[(nkt - 1) & 1], acc, wm, wn, lr, lg);

#pragma unroll
  for (int i = 0; i < 8; ++i) {
    const int row = bm + wm + i * 16 + lg * 4;  // + e
#pragma unroll
    for (int j = 0; j < 4; ++j) {
      const int col = bn + wn + j * 16 + lr;
      if (EPI == 1) {
        float* C = (float*)Cv;
        const float bs = bias[col];
#pragma unroll
        for (int e = 0; e < 4; ++e)
          C[(size_t)(row + e) * N + col] =
              acc[i][j][e] + bs + res[(size_t)(row + e) * N + col];
      } else {
        u16* C = (u16*)Cv;
        const float bs = bias[col];
#pragma unroll
        for (int e = 0; e < 4; ++e)
          C[(size_t)(row + e) * N + col] = f2bf(gelu_tanh(acc[i][j][e] + bs));
      }
    }
  }
}

// ---------------- Flash attention: 32x32 swapped, zero-LDS (round 8) -------
DEV float vmax16(const f32x16& v) {
  float a = fmaxf(v[0], v[1]), b = fmaxf(v[2], v[3]);
  float c = fmaxf(v[4], v[5]), d = fmaxf(v[6], v[7]);
  float e = fmaxf(v[8], v[9]), f = fmaxf(v[10], v[11]);
  float g = fmaxf(v[12], v[13]), h = fmaxf(v[14], v[15]);
  a = fmaxf(a, b); c = fmaxf(c, d); e = fmaxf(e, f); g = fmaxf(g, h);
  return fmaxf(fmaxf(a, c), fmaxf(e, g));
}
DEV float vsum16(const f32x16& v) {
  float a = v[0] + v[1], b = v[2] + v[3];
  float c = v[4] + v[5], d = v[6] + v[7];
  float e = v[8] + v[9], f = v[10] + v[11];
  float g = v[12] + v[13], h = v[14] + v[15];
  a += b; c += d; e += f; g += h;
  return (a + c) + (e + g);
}

struct A32 {
  s16x8 q[4];
  f32x16 o0, o1;
  float m, l;
};

template <int MODE>  // 0 interior, 1 full-diag, 2 half-tile
DEV void body32(A32& st, int k0, const u16* Kb, const u16* Vb, int la,
                int hi) {
  s16x8 ka0[4], ka1[4];
#pragma unroll
  for (int c = 0; c < 4; ++c)
    ka0[c] = ld8(Kb + (size_t)(k0 + la) * 64 + c * 16 + hi * 8);
  if (MODE != 2)
#pragma unroll
    for (int c = 0; c < 4; ++c)
      ka1[c] = ld8(Kb + (size_t)(k0 + 32 + la) * 64 + c * 16 + hi * 8);
  f32x16 s0, s1;
#pragma unroll
  for (int r = 0; r < 16; ++r) { s0[r] = 0.f; s1[r] = 0.f; }
#pragma unroll
  for (int c = 0; c < 4; ++c) s0 = MFMA32(ka0[c], st.q[c], s0, 0, 0, 0);
  if (MODE != 2)
#pragma unroll
    for (int c = 0; c < 4; ++c) s1 = MFMA32(ka1[c], st.q[c], s1, 0, 0, 0);
  const int nkc = (MODE == 2) ? 2 : 4;
  s16x8 va0[4], va1[4];
#pragma unroll
  for (int kc = 0; kc < 4; ++kc)
    if (kc < nkc) {
      va0[kc] = ld8(Vb + (size_t)la * 2048 + k0 + kc * 16 + hi * 8);
      va1[kc] = ld8(Vb + (size_t)(32 + la) * 2048 + k0 + kc * 16 + hi * 8);
    }
  if (MODE == 1) {
#pragma unroll
    for (int r = 0; r < 16; ++r) {
      const int kl = (r & 3) + 8 * (r >> 2) + 4 * hi;
      if (kl > la) s1[r] = -INFINITY;
    }
  }
  if (MODE == 2) {
#pragma unroll
    for (int r = 0; r < 16; ++r) {
      const int kl = (r & 3) + 8 * (r >> 2) + 4 * hi;
      if (kl > la) s0[r] = -INFINITY;
    }
  }
  float mt = vmax16(s0);
  if (MODE != 2) mt = fmaxf(mt, vmax16(s1));
  mt = fmaxf(mt, __shfl_xor(mt, 32));
  const float mn = fmaxf(st.m, mt);
  const float sf = exp2f(st.m - mn);
#pragma unroll
  for (int r = 0; r < 16; ++r) s0[r] = exp2f(s0[r] - mn);
  if (MODE != 2)
#pragma unroll
    for (int r = 0; r < 16; ++r) s1[r] = exp2f(s1[r] - mn);
  float rs = vsum16(s0);
  if (MODE != 2) rs += vsum16(s1);
  rs += __shfl_xor(rs, 32);
  st.l = st.l * sf + rs;
  st.m = mn;
#pragma unroll
  for (int r = 0; r < 16; ++r) { st.o0[r] *= sf; st.o1[r] *= sf; }
  const int nh = (MODE == 2) ? 1 : 2;
#pragma unroll
  for (int half = 0; half < nh; ++half) {
    u32 w[8];
#pragma unroll
    for (int i = 0; i < 8; ++i)
      w[i] = half ? cvtpk(s1[2 * i], s1[2 * i + 1])
                  : cvtpk(s0[2 * i], s0[2 * i + 1]);
#pragma unroll
    for (int kp = 0; kp < 2; ++kp) {
      const u32 w0 = w[4 * kp + 0], w1 = w[4 * kp + 1];
      const u32 w2 = w[4 * kp + 2], w3 = w[4 * kp + 3];
      const u32 t0 = hi ? w0 : w2, t1 = hi ? w1 : w3;
      const u32 x0 = (u32)__shfl_xor((int)t0, 32);
      const u32 x1 = (u32)__shfl_xor((int)t1, 32);
      union { u32 u[4]; s16x8 v; } bb;
      bb.u[0] = hi ? x0 : w0;
      bb.u[1] = hi ? x1 : w1;
      bb.u[2] = hi ? w2 : x0;
      bb.u[3] = hi ? w3 : x1;
      const int kc = half * 2 + kp;
      st.o0 = MFMA32(va0[kc], bb.v, st.o0, 0, 0, 0);
      st.o1 = MFMA32(va1[kc], bb.v, st.o1, 0, 0, 0);
    }
  }
}

__global__ __launch_bounds__(64, 2) void attn_kernel(
    const u16* __restrict__ Qg, const u16* __restrict__ Kg,
    const u16* __restrict__ Vt, u16* __restrict__ ctx) {
  const int lane = threadIdx.x & 63;
  const int la = lane & 31, hi = lane >> 5;
  const int bh = blockIdx.x & 31;
  const int qc = 63 - (blockIdx.x >> 5);  // heavy q-chunks dispatch first
  const int qs = qc * 32;
  const size_t baseK = (size_t)bh * 2048 * 64;
  const size_t baseV = (size_t)bh * 64 * 2048;
  const u16* Kb = Kg + baseK;
  const u16* Vb = Vt + baseV;

  A32 st;
#pragma unroll
  for (int c = 0; c < 4; ++c)
    st.q[c] = ld8(Qg + baseK + (size_t)(qs + la) * 64 + c * 16 + hi * 8);
#pragma unroll
  for (int r = 0; r < 16; ++r) { st.o0[r] = 0.f; st.o1[r] = 0.f; }
  st.m = -INFINITY;
  st.l = 0.f;

  const int nfull = qs >> 6;
  for (int kt = 0; kt < nfull; ++kt) body32<0>(st, kt * 64, Kb, Vb, la, hi);
  if (qs & 32) body32<1>(st, nfull * 64, Kb, Vb, la, hi);
  else         body32<2>(st, qs, Kb, Vb, la, hi);

  const int bb = bh >> 4, hh = bh & 15;
  const float inv = 1.0f / st.l;
  u16* crow = ctx + (size_t)(bb * 2048 + qs + la) * 1024 + hh * 64;
#pragma unroll
  for (int r = 0; r < 16; r += 2) {
    const int d = (r & 3) + 8 * (r >> 2) + 4 * hi;
    *(u32*)(crow + d) = cvtpk(st.o0[r] * inv, st.o0[r + 1] * inv);
    *(u32*)(crow + 32 + d) = cvtpk(st.o1[r] * inv, st.o1[r + 1] * inv);
  }
}

// ---------------------------------------------------------------------------
extern "C" void kernel_launch(void* const* d_in, const int* in_sizes, int n_in,
                              void* d_out, int out_size, void* d_ws,
                              size_t ws_size, hipStream_t stream) {
  const float* x  = (const float*)d_in[0];
  const float* wq = (const float*)d_in[1];
  const float* wk = (const float*)d_in[2];
  const float* wv = (const float*)d_in[3];
  const float* wo = (const float*)d_in[4];
  const float* bo = (const float*)d_in[5];
  const float* w1 = (const float*)d_in[6];
  const float* b1 = (const float*)d_in[7];
  const float* w2 = (const float*)d_in[8];
  const float* b2 = (const float*)d_in[9];
  const float* g1 = (const float*)d_in[10];
  const float* s1 = (const float*)d_in[11];
  const float* g2 = (const float*)d_in[12];
  const float* s2 = (const float*)d_in[13];
  float* out = (float*)d_out;

  const size_t MB = (size_t)1 << 20;
  char* p = (char*)d_ws;
  u16* hb    = (u16*)(p + 0 * MB);    // LN1 out (dead after QKV)
  u16* qbuf  = (u16*)(p + 8 * MB);    // q | k [32][2048][64], vt [32][64][2048]
  u16* ctxb  = (u16*)(p + 32 * MB);
  float* x2  = (float*)(p + 40 * MB); // residual fp32 (16MB)
  u16* h2b   = (u16*)(p + 56 * MB);   // LN2 out (8MB)
  u16* qkvw  = (u16*)(p + 64 * MB);   // [3072][1024] packed Wq/Wk/Wv^T (6MB)
  u16* wot   = (u16*)(p + 70 * MB);
  u16* w1t   = (u16*)(p + 72 * MB);
  u16* w2t   = (u16*)(p + 80 * MB);
  u16* gb    = (u16*)(p + 0 * MB);    // gelu out, aliases hb/qbuf (32MB)

  const dim3 blk(256);
  tconv_kernel<<<dim3(16, 16), blk, 0, stream>>>(wq, qkvw, 1024, 1024);
  tconv_kernel<<<dim3(16, 16), blk, 0, stream>>>(wk, qkvw + 1048576, 1024, 1024);
  tconv_kernel<<<dim3(16, 16), blk, 0, stream>>>(wv, qkvw + 2097152, 1024, 1024);
  tconv_kernel<<<dim3(16, 16), blk, 0, stream>>>(wo, wot, 1024, 1024);
  tconv_kernel<<<dim3(64, 16), blk, 0, stream>>>(w1, w1t, 1024, 4096);
  tconv_kernel<<<dim3(16, 64), blk, 0, stream>>>(w2, w2t, 4096, 1024);

  ln_kernel<<<4096, blk, 0, stream>>>(x, g1, s1, hb);
  gemm_kernel<0><<<dim3(24, 32), blk, 0, stream>>>(hb, qkvw, nullptr, nullptr,
                                                   qbuf, 4096, 3072, 1024);
  attn_kernel<<<dim3(2048), dim3(64), 0, stream>>>(
      qbuf, qbuf + 4194304, qbuf + 8388608, ctxb);
  gemm64_kernel<1><<<dim3(16, 64), blk, 0, stream>>>(ctxb, wot, bo, x, x2,
                                                     4096, 1024, 1024);
  ln_kernel<<<4096, blk, 0, stream>>>(x2, g2, s2, h2b);
  gemm256_kernel<2><<<dim3(16, 16), dim3(512), 0, stream>>>(
      h2b, w1t, b1, nullptr, gb, 4096, 4096, 1024);
  gemm64_kernel<1><<<dim3(16, 64), blk, 0, stream>>>(gb, w2t, b2, x2, out,
                                                     4096, 1024, 4096);
}

// Round 11
// 302.492 us; speedup vs baseline: 1.4569x; 1.0158x over previous
//
#include <hip/hip_runtime.h>

// TransformerBlock: B=2, S=2048, D=1024, H=16, dh=64, FFN=4096.
// Round 11: dual-chain lockstep 32x32 attention (pair q-chunks t & 63-t,
// ILP=2 in one wave). GEMMs unchanged from round 10.

typedef __attribute__((ext_vector_type(8))) short s16x8;
typedef __attribute__((ext_vector_type(4))) float f32x4;
typedef __attribute__((ext_vector_type(16))) float f32x16;
typedef unsigned short u16;
typedef unsigned int u32;

#define DEV static __device__ __forceinline__
#define MFMA16 __builtin_amdgcn_mfma_f32_16x16x32_bf16
#define MFMA32 __builtin_amdgcn_mfma_f32_32x32x16_bf16
#define GLOAD_LDS16(gp, lp)                                         \
  __builtin_amdgcn_global_load_lds(                                 \
      (const __attribute__((address_space(1))) void*)(gp),          \
      (__attribute__((address_space(3))) void*)(lp), 16, 0, 0)

DEV u16 f2bf(float f) {
  union { float f; unsigned u; } c; c.f = f;
  unsigned u = c.u;
  u += 0x7fff + ((u >> 16) & 1);   // RNE
  return (u16)(u >> 16);
}

DEV u32 cvtpk(float lo, float hi) {  // packed f32x2 -> bf16x2 (RNE)
  u32 r;
  asm("v_cvt_pk_bf16_f32 %0, %1, %2" : "=v"(r) : "v"(lo), "v"(hi));
  return r;
}

DEV float gelu_tanh(float v) {
  const float c0 = 0.7978845608028654f;  // sqrt(2/pi)
  float u = c0 * (v + 0.044715f * v * v * v);
  return 0.5f * v * (1.0f + tanhf(u));
}

DEV s16x8 ld8(const u16* p) { return *(const s16x8*)p; }

// ---------- transpose + convert: W fp32 [K,N] -> Wt bf16 [N,K] -------------
__global__ __launch_bounds__(256) void tconv_kernel(
    const float* __restrict__ W, u16* __restrict__ Wt, int K, int N) {
  __shared__ u16 T[64][80];
  const int t = threadIdx.x;
  const int n0 = blockIdx.x * 64, k0 = blockIdx.y * 64;
  const int kr = t >> 4, nc = (t & 15) * 4;
#pragma unroll
  for (int p = 0; p < 4; ++p) {
    const int k = p * 16 + kr;
    float4 v = *(const float4*)(W + (size_t)(k0 + k) * N + n0 + nc);
    T[nc + 0][k] = f2bf(v.x);
    T[nc + 1][k] = f2bf(v.y);
    T[nc + 2][k] = f2bf(v.z);
    T[nc + 3][k] = f2bf(v.w);
  }
  __syncthreads();
  const int nr = t >> 2, kc = (t & 3) * 16;
  *(s16x8*)(Wt + (size_t)(n0 + nr) * K + k0 + kc) = *(const s16x8*)&T[nr][kc];
  *(s16x8*)(Wt + (size_t)(n0 + nr) * K + k0 + kc + 8) =
      *(const s16x8*)&T[nr][kc + 8];
}

// ---------------- LayerNorm: fp32 [rows,1024] -> bf16 [rows,1024] ----------
__global__ __launch_bounds__(256) void ln_kernel(
    const float* __restrict__ x, const float* __restrict__ g,
    const float* __restrict__ b, u16* __restrict__ out) {
  const int row = blockIdx.x;
  const int t = threadIdx.x;
  const float* xr = x + (size_t)row * 1024;
  float4 v = *(const float4*)(xr + t * 4);
  float s = v.x + v.y + v.z + v.w;
  float ss = v.x * v.x + v.y * v.y + v.z * v.z + v.w * v.w;
#pragma unroll
  for (int off = 1; off < 64; off <<= 1) {
    s += __shfl_xor(s, off);
    ss += __shfl_xor(ss, off);
  }
  __shared__ float sb[4], ssb[4];
  const int w = t >> 6;
  if ((t & 63) == 0) { sb[w] = s; ssb[w] = ss; }
  __syncthreads();
  s = sb[0] + sb[1] + sb[2] + sb[3];
  ss = ssb[0] + ssb[1] + ssb[2] + ssb[3];
  const float mean = s * (1.0f / 1024.0f);
  const float var = ss * (1.0f / 1024.0f) - mean * mean;
  const float rstd = rsqrtf(var + 1e-5f);
  const int c = t * 4;
  ushort4 o;
  o.x = f2bf(g[c + 0] * ((v.x - mean) * rstd) + b[c + 0]);
  o.y = f2bf(g[c + 1] * ((v.y - mean) * rstd) + b[c + 1]);
  o.z = f2bf(g[c + 2] * ((v.z - mean) * rstd) + b[c + 2]);
  o.w = f2bf(g[c + 3] * ((v.w - mean) * rstd) + b[c + 3]);
  *(ushort4*)(out + (size_t)row * 1024 + c) = o;
}

// ---- XOR swizzle (64B LDS rows, 16B slots): phys_slot = log_slot ^ sw(row),
// sw(row) = (row>>1)&3. Write side pre-swizzles the GLOBAL source col since
// global_load_lds writes linearly.
// ---------------- GEMM 128^2 -----------------------------------------------
DEV void gemm_stage(const u16* __restrict__ A, const u16* __restrict__ Bt,
                    int bm, int bn, int K, int kof, u16 (*Al)[32],
                    u16 (*Bl)[32], int w, int lane) {
  const int srow = lane >> 2;
  const int scol = ((lane & 3) ^ ((lane >> 3) & 3)) * 8;  // swizzled source
#pragma unroll
  for (int p = 0; p < 2; ++p) {
    const int r0 = (w * 2 + p) * 16;
    GLOAD_LDS16(A + (size_t)(bm + r0 + srow) * K + kof + scol, &Al[r0][0]);
    GLOAD_LDS16(Bt + (size_t)(bn + r0 + srow) * K + kof + scol, &Bl[r0][0]);
  }
}

DEV void gemm_step(const u16 (*Al)[32], const u16 (*Bl)[32],
                   f32x4 (&acc)[4][4], int wm, int wn, int lr, int lg) {
  const int cs = (lg ^ ((lr >> 1) & 3)) * 8;  // swizzled read col
  s16x8 af[4], bf[4];
#pragma unroll
  for (int i = 0; i < 4; ++i) {
    af[i] = *(const s16x8*)&Al[wm + i * 16 + lr][cs];
    bf[i] = *(const s16x8*)&Bl[wn + i * 16 + lr][cs];
  }
#pragma unroll
  for (int i = 0; i < 4; ++i)
#pragma unroll
    for (int j = 0; j < 4; ++j)
      acc[i][j] = MFMA16(af[i], bf[j], acc[i][j], 0, 0, 0);
}

template <int EPI>
__global__ __launch_bounds__(256) void gemm_kernel(
    const u16* __restrict__ A, const u16* __restrict__ Bt,
    const float* __restrict__ bias, const float* __restrict__ res,
    void* __restrict__ Cv, int M, int N, int K) {
  __shared__ __align__(16) u16 Al[2][128][32];
  __shared__ __align__(16) u16 Bl[2][128][32];
  const int t = threadIdx.x;
  const int lane = t & 63, w = t >> 6;
  const int wm = (w >> 1) * 64, wn = (w & 1) * 64;
  int bid = blockIdx.y * gridDim.x + blockIdx.x;
  const int q8 = (gridDim.x * gridDim.y) >> 3;
  bid = (bid & 7) * q8 + (bid >> 3);
  const int bm = (bid / gridDim.x) * 128, bn = (bid % gridDim.x) * 128;
  const int lr = lane & 15, lg = lane >> 4;
  f32x4 acc[4][4] = {};
  const int nkt = K >> 5;

  gemm_stage(A, Bt, bm, bn, K, 0, Al[0], Bl[0], w, lane);
  __syncthreads();
  for (int kt = 0; kt < nkt - 1; ++kt) {
    const int cur = kt & 1;
    gemm_stage(A, Bt, bm, bn, K, (kt + 1) << 5, Al[cur ^ 1], Bl[cur ^ 1], w,
               lane);
    gemm_step(Al[cur], Bl[cur], acc, wm, wn, lr, lg);
    __syncthreads();
  }
  gemm_step(Al[(nkt - 1) & 1], Bl[(nkt - 1) & 1], acc, wm, wn, lr, lg);

#pragma unroll
  for (int i = 0; i < 4; ++i) {
    const int row = bm + wm + i * 16 + lg * 4;  // + e
#pragma unroll
    for (int j = 0; j < 4; ++j) {
      const int col = bn + wn + j * 16 + lr;
      if (EPI == 0) {
        const int bb = row >> 11, sloc = row & 2047;
        const int which = col >> 10, n = col & 1023;
        const int hh = n >> 6, dd = n & 63;
        u16* qbuf = (u16*)Cv;
        if (which == 2) {  // V transposed [bh][64][2048]
          ushort4 o;
          o.x = f2bf(acc[i][j][0]); o.y = f2bf(acc[i][j][1]);
          o.z = f2bf(acc[i][j][2]); o.w = f2bf(acc[i][j][3]);
          *(ushort4*)(qbuf + 8388608 +
                      (size_t)((bb * 16 + hh) * 64 + dd) * 2048 + sloc) = o;
        } else {
          // q pre-scaled by (1/8)*log2(e) so attention runs in exp2 space
          const float sc = (which == 0) ? 0.18033688011112042f : 1.0f;
          u16* dst = qbuf + (size_t)which * 4194304 +
                     ((size_t)(bb * 16 + hh) * 2048 + sloc) * 64 + dd;
#pragma unroll
          for (int e = 0; e < 4; ++e) dst[(size_t)e * 64] = f2bf(acc[i][j][e] * sc);
        }
      } else if (EPI == 1) {
        float* C = (float*)Cv;
        const float bs = bias[col];
#pragma unroll
        for (int e = 0; e < 4; ++e)
          C[(size_t)(row + e) * N + col] =
              acc[i][j][e] + bs + res[(size_t)(row + e) * N + col];
      } else {
        u16* C = (u16*)Cv;
        const float bs = bias[col];
#pragma unroll
        for (int e = 0; e < 4; ++e)
          C[(size_t)(row + e) * N + col] = f2bf(gelu_tanh(acc[i][j][e] + bs));
      }
    }
  }
}

// ---------------- GEMM 64^2: 4 waves, wave-tile 32x32, 4 blocks/CU ---------
DEV void g64_stage(const u16* __restrict__ A, const u16* __restrict__ Bt,
                   int bm, int bn, int K, int kof, u16 (*Al)[32],
                   u16 (*Bl)[32], int w, int lane) {
  const int srow = lane >> 2;
  const int scol = ((lane & 3) ^ ((lane >> 3) & 3)) * 8;
  const int r0 = w << 4;
  GLOAD_LDS16(A + (size_t)(bm + r0 + srow) * K + kof + scol, &Al[r0][0]);
  GLOAD_LDS16(Bt + (size_t)(bn + r0 + srow) * K + kof + scol, &Bl[r0][0]);
}

DEV void g64_step(const u16 (*Al)[32], const u16 (*Bl)[32],
                  f32x4 (&acc)[2][2], int wm, int wn, int lr, int lg) {
  const int cs = (lg ^ ((lr >> 1) & 3)) * 8;
  s16x8 af[2], bf[2];
#pragma unroll
  for (int i = 0; i < 2; ++i) {
    af[i] = *(const s16x8*)&Al[wm + i * 16 + lr][cs];
    bf[i] = *(const s16x8*)&Bl[wn + i * 16 + lr][cs];
  }
#pragma unroll
  for (int i = 0; i < 2; ++i)
#pragma unroll
    for (int j = 0; j < 2; ++j)
      acc[i][j] = MFMA16(af[i], bf[j], acc[i][j], 0, 0, 0);
}

template <int EPI>
__global__ __launch_bounds__(256) void gemm64_kernel(
    const u16* __restrict__ A, const u16* __restrict__ Bt,
    const float* __restrict__ bias, const float* __restrict__ res,
    void* __restrict__ Cv, int M, int N, int K) {
  __shared__ __align__(16) u16 Al[2][64][32];
  __shared__ __align__(16) u16 Bl[2][64][32];
  const int t = threadIdx.x;
  const int lane = t & 63, w = t >> 6;
  const int wm = (w >> 1) * 32, wn = (w & 1) * 32;
  int bid = blockIdx.y * gridDim.x + blockIdx.x;
  const int q8 = (gridDim.x * gridDim.y) >> 3;
  bid = (bid & 7) * q8 + (bid >> 3);
  const int bm = (bid / gridDim.x) * 64, bn = (bid % gridDim.x) * 64;
  const int lr = lane & 15, lg = lane >> 4;
  f32x4 acc[2][2] = {};
  const int nkt = K >> 5;

  g64_stage(A, Bt, bm, bn, K, 0, Al[0], Bl[0], w, lane);
  __syncthreads();
  for (int kt = 0; kt < nkt - 1; ++kt) {
    const int cur = kt & 1;
    g64_stage(A, Bt, bm, bn, K, (kt + 1) << 5, Al[cur ^ 1], Bl[cur ^ 1], w,
              lane);
    g64_step(Al[cur], Bl[cur], acc, wm, wn, lr, lg);
    __syncthreads();
  }
  g64_step(Al[(nkt - 1) & 1], Bl[(nkt - 1) & 1], acc, wm, wn, lr, lg);

#pragma unroll
  for (int i = 0; i < 2; ++i) {
    const int row = bm + wm + i * 16 + lg * 4;  // + e
#pragma unroll
    for (int j = 0; j < 2; ++j) {
      const int col = bn + wn + j * 16 + lr;
      if (EPI == 1) {
        float* C = (float*)Cv;
        const float bs = bias[col];
#pragma unroll
        for (int e = 0; e < 4; ++e)
          C[(size_t)(row + e) * N + col] =
              acc[i][j][e] + bs + res[(size_t)(row + e) * N + col];
      } else {
        u16* C = (u16*)Cv;
        const float bs = bias[col];
#pragma unroll
        for (int e = 0; e < 4; ++e)
          C[(size_t)(row + e) * N + col] = f2bf(gelu_tanh(acc[i][j][e] + bs));
      }
    }
  }
}

// ---------------- GEMM 256^2: 8 waves, wave-tile 128x64, BK=32 -------------
DEV void g256_stage(const u16* __restrict__ A, const u16* __restrict__ Bt,
                    int bm, int bn, int K, int kof, u16 (*Al)[32],
                    u16 (*Bl)[32], int w, int lane) {
  const int srow = lane >> 2;
  const int scol = ((lane & 3) ^ ((lane >> 3) & 3)) * 8;
#pragma unroll
  for (int c = 0; c < 2; ++c) {
    const int r0 = (w << 5) + (c << 4);
    GLOAD_LDS16(A + (size_t)(bm + r0 + srow) * K + kof + scol, &Al[r0][0]);
    GLOAD_LDS16(Bt + (size_t)(bn + r0 + srow) * K + kof + scol, &Bl[r0][0]);
  }
}

DEV void g256_step(const u16 (*Al)[32], const u16 (*Bl)[32],
                   f32x4 (&acc)[8][4], int wm, int wn, int lr, int lg) {
  const int cs = (lg ^ ((lr >> 1) & 3)) * 8;
  s16x8 af[8], bf[4];
#pragma unroll
  for (int i = 0; i < 8; ++i)
    af[i] = *(const s16x8*)&Al[wm + i * 16 + lr][cs];
#pragma unroll
  for (int j = 0; j < 4; ++j)
    bf[j] = *(const s16x8*)&Bl[wn + j * 16 + lr][cs];
#pragma unroll
  for (int i = 0; i < 8; ++i)
#pragma unroll
    for (int j = 0; j < 4; ++j)
      acc[i][j] = MFMA16(af[i], bf[j], acc[i][j], 0, 0, 0);
}

template <int EPI>
__global__ __launch_bounds__(512, 2) void gemm256_kernel(
    const u16* __restrict__ A, const u16* __restrict__ Bt,
    const float* __restrict__ bias, const float* __restrict__ res,
    void* __restrict__ Cv, int M, int N, int K) {
  __shared__ __align__(16) u16 Al[2][256][32];
  __shared__ __align__(16) u16 Bl[2][256][32];
  const int t = threadIdx.x;
  const int lane = t & 63, w = t >> 6;           // 8 waves
  const int wm = (w >> 2) << 7;                  // 0 / 128
  const int wn = (w & 3) << 6;                   // 0/64/128/192
  int bid = blockIdx.y * gridDim.x + blockIdx.x;
  const int q8 = (gridDim.x * gridDim.y) >> 3;
  bid = (bid & 7) * q8 + (bid >> 3);
  const int bm = (bid / gridDim.x) << 8, bn = (bid % gridDim.x) << 8;
  const int lr = lane & 15, lg = lane >> 4;
  f32x4 acc[8][4] = {};
  const int nkt = K >> 5;

  g256_stage(A, Bt, bm, bn, K, 0, Al[0], Bl[0], w, lane);
  __syncthreads();
  for (int kt = 0; kt < nkt - 1; ++kt) {
    const int cur = kt & 1;
    g256_stage(A, Bt, bm, bn, K, (kt + 1) << 5, Al[cur ^ 1], Bl[cur ^ 1], w,
               lane);
    g256_step(Al[cur], Bl[cur], acc, wm, wn, lr, lg);
    __syncthreads();
  }
  g256_step(Al[(nkt - 1) & 1], Bl[(nkt - 1) & 1], acc, wm, wn, lr, lg);

#pragma unroll
  for (int i = 0; i < 8; ++i) {
    const int row = bm + wm + i * 16 + lg * 4;  // + e
#pragma unroll
    for (int j = 0; j < 4; ++j) {
      const int col = bn + wn + j * 16 + lr;
      if (EPI == 1) {
        float* C = (float*)Cv;
        const float bs = bias[col];
#pragma unroll
        for (int e = 0; e < 4; ++e)
          C[(size_t)(row + e) * N + col] =
              acc[i][j][e] + bs + res[(size_t)(row + e) * N + col];
      } else {
        u16* C = (u16*)Cv;
        const float bs = bias[col];
#pragma unroll
        for (int e = 0; e < 4; ++e)
          C[(size_t)(row + e) * N + col] = f2bf(gelu_tanh(acc[i][j][e] + bs));
      }
    }
  }
}

// ---------------- Flash attention: 32x32 swapped, zero-LDS, dual-chain -----
DEV float vmax16(const f32x16& v) {
  float a = fmaxf(v[0], v[1]), b = fmaxf(v[2], v[3]);
  float c = fmaxf(v[4], v[5]), d = fmaxf(v[6], v[7]);
  float e = fmaxf(v[8], v[9]), f = fmaxf(v[10], v[11]);
  float g = fmaxf(v[12], v[13]), h = fmaxf(v[14], v[15]);
  a = fmaxf(a, b); c = fmaxf(c, d); e = fmaxf(e, f); g = fmaxf(g, h);
  return fmaxf(fmaxf(a, c), fmaxf(e, g));
}
DEV float vsum16(const f32x16& v) {
  float a = v[0] + v[1], b = v[2] + v[3];
  float c = v[4] + v[5], d = v[6] + v[7];
  float e = v[8] + v[9], f = v[10] + v[11];
  float g = v[12] + v[13], h = v[14] + v[15];
  a += b; c += d; e += f; g += h;
  return (a + c) + (e + g);
}

struct A32 {
  s16x8 q[4];
  f32x16 o0, o1;
  float m, l;
};

template <int MODE>  // 0 interior, 1 full-diag, 2 half-tile
DEV void body32(A32& st, int k0, const u16* Kb, const u16* Vb, int la,
                int hi) {
  s16x8 ka0[4], ka1[4];
#pragma unroll
  for (int c = 0; c < 4; ++c)
    ka0[c] = ld8(Kb + (size_t)(k0 + la) * 64 + c * 16 + hi * 8);
  if (MODE != 2)
#pragma unroll
    for (int c = 0; c < 4; ++c)
      ka1[c] = ld8(Kb + (size_t)(k0 + 32 + la) * 64 + c * 16 + hi * 8);
  f32x16 s0, s1;
#pragma unroll
  for (int r = 0; r < 16; ++r) { s0[r] = 0.f; s1[r] = 0.f; }
#pragma unroll
  for (int c = 0; c < 4; ++c) s0 = MFMA32(ka0[c], st.q[c], s0, 0, 0, 0);
  if (MODE != 2)
#pragma unroll
    for (int c = 0; c < 4; ++c) s1 = MFMA32(ka1[c], st.q[c], s1, 0, 0, 0);
  const int nkc = (MODE == 2) ? 2 : 4;
  s16x8 va0[4], va1[4];
#pragma unroll
  for (int kc = 0; kc < 4; ++kc)
    if (kc < nkc) {
      va0[kc] = ld8(Vb + (size_t)la * 2048 + k0 + kc * 16 + hi * 8);
      va1[kc] = ld8(Vb + (size_t)(32 + la) * 2048 + k0 + kc * 16 + hi * 8);
    }
  if (MODE == 1) {
#pragma unroll
    for (int r = 0; r < 16; ++r) {
      const int kl = (r & 3) + 8 * (r >> 2) + 4 * hi;
      if (kl > la) s1[r] = -INFINITY;
    }
  }
  if (MODE == 2) {
#pragma unroll
    for (int r = 0; r < 16; ++r) {
      const int kl = (r & 3) + 8 * (r >> 2) + 4 * hi;
      if (kl > la) s0[r] = -INFINITY;
    }
  }
  float mt = vmax16(s0);
  if (MODE != 2) mt = fmaxf(mt, vmax16(s1));
  mt = fmaxf(mt, __shfl_xor(mt, 32));
  const float mn = fmaxf(st.m, mt);
  const float sf = exp2f(st.m - mn);
#pragma unroll
  for (int r = 0; r < 16; ++r) s0[r] = exp2f(s0[r] - mn);
  if (MODE != 2)
#pragma unroll
    for (int r = 0; r < 16; ++r) s1[r] = exp2f(s1[r] - mn);
  float rs = vsum16(s0);
  if (MODE != 2) rs += vsum16(s1);
  rs += __shfl_xor(rs, 32);
  st.l = st.l * sf + rs;
  st.m = mn;
#pragma unroll
  for (int r = 0; r < 16; ++r) { st.o0[r] *= sf; st.o1[r] *= sf; }
  const int nh = (MODE == 2) ? 1 : 2;
#pragma unroll
  for (int half = 0; half < nh; ++half) {
    u32 w[8];
#pragma unroll
    for (int i = 0; i < 8; ++i)
      w[i] = half ? cvtpk(s1[2 * i], s1[2 * i + 1])
                  : cvtpk(s0[2 * i], s0[2 * i + 1]);
#pragma unroll
    for (int kp = 0; kp < 2; ++kp) {
      const u32 w0 = w[4 * kp + 0], w1 = w[4 * kp + 1];
      const u32 w2 = w[4 * kp + 2], w3 = w[4 * kp + 3];
      const u32 t0 = hi ? w0 : w2, t1 = hi ? w1 : w3;
      const u32 x0 = (u32)__shfl_xor((int)t0, 32);
      const u32 x1 = (u32)__shfl_xor((int)t1, 32);
      union { u32 u[4]; s16x8 v; } bb;
      bb.u[0] = hi ? x0 : w0;
      bb.u[1] = hi ? x1 : w1;
      bb.u[2] = hi ? w2 : x0;
      bb.u[3] = hi ? w3 : x1;
      const int kc = half * 2 + kp;
      st.o0 = MFMA32(va0[kc], bb.v, st.o0, 0, 0, 0);
      st.o1 = MFMA32(va1[kc], bb.v, st.o1, 0, 0, 0);
    }
  }
}

DEV void a32_init(A32& st, const u16* Qbase, int qs, int la, int hi) {
#pragma unroll
  for (int c = 0; c < 4; ++c)
    st.q[c] = ld8(Qbase + (size_t)(qs + la) * 64 + c * 16 + hi * 8);
#pragma unroll
  for (int r = 0; r < 16; ++r) { st.o0[r] = 0.f; st.o1[r] = 0.f; }
  st.m = -INFINITY;
  st.l = 0.f;
}

DEV void a32_fin(const A32& st, u16* __restrict__ ctx, int bh, int qs, int la,
                 int hi) {
  const int bb = bh >> 4, hh = bh & 15;
  const float inv = 1.0f / st.l;
  u16* crow = ctx + (size_t)(bb * 2048 + qs + la) * 1024 + hh * 64;
#pragma unroll
  for (int r = 0; r < 16; r += 2) {
    const int d = (r & 3) + 8 * (r >> 2) + 4 * hi;
    *(u32*)(crow + d) = cvtpk(st.o0[r] * inv, st.o0[r + 1] * inv);
    *(u32*)(crow + 32 + d) = cvtpk(st.o1[r] * inv, st.o1[r + 1] * inv);
  }
}

// Chain X finishes with MODE1 (odd q-chunk) or MODE2 (even q-chunk).
template <bool ODD>
DEV void chain_tail(A32& st, int nfull, int qs, const u16* Kb, const u16* Vb,
                    int la, int hi) {
  if (ODD) body32<1>(st, nfull * 64, Kb, Vb, la, hi);
  else     body32<2>(st, qs, Kb, Vb, la, hi);
}

__global__ __launch_bounds__(64) void attn_kernel(
    const u16* __restrict__ Qg, const u16* __restrict__ Kg,
    const u16* __restrict__ Vt, u16* __restrict__ ctx) {
  const int lane = threadIdx.x & 63;
  const int la = lane & 31, hi = lane >> 5;
  const int tA = blockIdx.x;            // 0..31: chain A = light q-chunk
  const int bh = blockIdx.y;
  const int tB = 63 - tA;               // chain B = heavy q-chunk
  const int qsA = tA * 32, qsB = tB * 32;
  const int nfA = tA >> 1, nfB = tB >> 1;  // interior (64-key) bodies
  const size_t baseK = (size_t)bh * 2048 * 64;
  const size_t baseV = (size_t)bh * 64 * 2048;
  const u16* Kb = Kg + baseK;
  const u16* Vb = Vt + baseV;

  A32 A, B;
  a32_init(A, Qg + baseK, qsA, la, hi);
  a32_init(B, Qg + baseK, qsB, la, hi);

  // lockstep: B interior || A interior, then B interior || A tail
  for (int kt = 0; kt < nfA; ++kt) {
    body32<0>(B, kt * 64, Kb, Vb, la, hi);
    body32<0>(A, kt * 64, Kb, Vb, la, hi);
  }
  body32<0>(B, nfA * 64, Kb, Vb, la, hi);
  if (tA & 1) chain_tail<true>(A, nfA, qsA, Kb, Vb, la, hi);
  else        chain_tail<false>(A, nfA, qsA, Kb, Vb, la, hi);
  a32_fin(A, ctx, bh, qsA, la, hi);

  // B solo
  for (int kt = nfA + 1; kt < nfB; ++kt)
    body32<0>(B, kt * 64, Kb, Vb, la, hi);
  if (tB & 1) chain_tail<true>(B, nfB, qsB, Kb, Vb, la, hi);
  else        chain_tail<false>(B, nfB, qsB, Kb, Vb, la, hi);
  a32_fin(B, ctx, bh, qsB, la, hi);
}

// ---------------------------------------------------------------------------
extern "C" void kernel_launch(void* const* d_in, const int* in_sizes, int n_in,
                              void* d_out, int out_size, void* d_ws,
                              size_t ws_size, hipStream_t stream) {
  const float* x  = (const float*)d_in[0];
  const float* wq = (const float*)d_in[1];
  const float* wk = (const float*)d_in[2];
  const float* wv = (const float*)d_in[3];
  const float* wo = (const float*)d_in[4];
  const float* bo = (const float*)d_in[5];
  const float* w1 = (const float*)d_in[6];
  const float* b1 = (const float*)d_in[7];
  const float* w2 = (const float*)d_in[8];
  const float* b2 = (const float*)d_in[9];
  const float* g1 = (const float*)d_in[10];
  const float* s1 = (const float*)d_in[11];
  const float* g2 = (const float*)d_in[12];
  const float* s2 = (const float*)d_in[13];
  float* out = (float*)d_out;

  const size_t MB = (size_t)1 << 20;
  char* p = (char*)d_ws;
  u16* hb    = (u16*)(p + 0 * MB);    // LN1 out (dead after QKV)
  u16* qbuf  = (u16*)(p + 8 * MB);    // q | k [32][2048][64], vt [32][64][2048]
  u16* ctxb  = (u16*)(p + 32 * MB);
  float* x2  = (float*)(p + 40 * MB); // residual fp32 (16MB)
  u16* h2b   = (u16*)(p + 56 * MB);   // LN2 out (8MB)
  u16* qkvw  = (u16*)(p + 64 * MB);   // [3072][1024] packed Wq/Wk/Wv^T (6MB)
  u16* wot   = (u16*)(p + 70 * MB);
  u16* w1t   = (u16*)(p + 72 * MB);
  u16* w2t   = (u16*)(p + 80 * MB);
  u16* gb    = (u16*)(p + 0 * MB);    // gelu out, aliases hb/qbuf (32MB)

  const dim3 blk(256);
  tconv_kernel<<<dim3(16, 16), blk, 0, stream>>>(wq, qkvw, 1024, 1024);
  tconv_kernel<<<dim3(16, 16), blk, 0, stream>>>(wk, qkvw + 1048576, 1024, 1024);
  tconv_kernel<<<dim3(16, 16), blk, 0, stream>>>(wv, qkvw + 2097152, 1024, 1024);
  tconv_kernel<<<dim3(16, 16), blk, 0, stream>>>(wo, wot, 1024, 1024);
  tconv_kernel<<<dim3(64, 16), blk, 0, stream>>>(w1, w1t, 1024, 4096);
  tconv_kernel<<<dim3(16, 64), blk, 0, stream>>>(w2, w2t, 4096, 1024);

  ln_kernel<<<4096, blk, 0, stream>>>(x, g1, s1, hb);
  gemm_kernel<0><<<dim3(24, 32), blk, 0, stream>>>(hb, qkvw, nullptr, nullptr,
                                                   qbuf, 4096, 3072, 1024);
  attn_kernel<<<dim3(32, 32), dim3(64), 0, stream>>>(
      qbuf, qbuf + 4194304, qbuf + 8388608, ctxb);
  gemm64_kernel<1><<<dim3(16, 64), blk, 0, stream>>>(ctxb, wot, bo, x, x2,
                                                     4096, 1024, 1024);
  ln_kernel<<<4096, blk, 0, stream>>>(x2, g2, s2, h2b);
  gemm256_kernel<2><<<dim3(16, 16), dim3(512), 0, stream>>>(
      h2b, w1t, b1, nullptr, gb, 4096, 4096, 1024);
  gemm64_kernel<1><<<dim3(16, 64), blk, 0, stream>>>(gb, w2t, b2, x2, out,
                                                     4096, 1024, 4096);
}

// Round 12
// 301.613 us; speedup vs baseline: 1.4611x; 1.0029x over previous
//
#include <hip/hip_runtime.h>

// TransformerBlock: B=2, S=2048, D=1024, H=16, dh=64, FFN=4096.
// Round 12: split-K + dual-chain attention (2048 balanced waves, ILP=2,
// partial combine), defer-max, fused weight-transpose. GEMMs from round 11.

typedef __attribute__((ext_vector_type(8))) short s16x8;
typedef __attribute__((ext_vector_type(4))) float f32x4;
typedef __attribute__((ext_vector_type(16))) float f32x16;
typedef unsigned short u16;
typedef unsigned int u32;

#define DEV static __device__ __forceinline__
#define MFMA16 __builtin_amdgcn_mfma_f32_16x16x32_bf16
#define MFMA32 __builtin_amdgcn_mfma_f32_32x32x16_bf16
#define GLOAD_LDS16(gp, lp)                                         \
  __builtin_amdgcn_global_load_lds(                                 \
      (const __attribute__((address_space(1))) void*)(gp),          \
      (__attribute__((address_space(3))) void*)(lp), 16, 0, 0)

DEV u16 f2bf(float f) {
  union { float f; unsigned u; } c; c.f = f;
  unsigned u = c.u;
  u += 0x7fff + ((u >> 16) & 1);   // RNE
  return (u16)(u >> 16);
}

DEV float bf2f(u16 v) {
  union { u32 u; float f; } c; c.u = (u32)v << 16;
  return c.f;
}

DEV u32 cvtpk(float lo, float hi) {  // packed f32x2 -> bf16x2 (RNE)
  u32 r;
  asm("v_cvt_pk_bf16_f32 %0, %1, %2" : "=v"(r) : "v"(lo), "v"(hi));
  return r;
}

DEV float gelu_tanh(float v) {
  const float c0 = 0.7978845608028654f;  // sqrt(2/pi)
  float u = c0 * (v + 0.044715f * v * v * v);
  return 0.5f * v * (1.0f + tanhf(u));
}

DEV s16x8 ld8(const u16* p) { return *(const s16x8*)p; }

// ---------- fused transpose+convert for all 6 weights ----------------------
DEV void tconv_tile(const float* __restrict__ W, u16* __restrict__ Wt, int K,
                    int N, int bx, int by, int t) {
  __shared__ u16 T[64][80];
  const int n0 = bx * 64, k0 = by * 64;
  const int kr = t >> 4, nc = (t & 15) * 4;
#pragma unroll
  for (int p = 0; p < 4; ++p) {
    const int k = p * 16 + kr;
    float4 v = *(const float4*)(W + (size_t)(k0 + k) * N + n0 + nc);
    T[nc + 0][k] = f2bf(v.x);
    T[nc + 1][k] = f2bf(v.y);
    T[nc + 2][k] = f2bf(v.z);
    T[nc + 3][k] = f2bf(v.w);
  }
  __syncthreads();
  const int nr = t >> 2, kc = (t & 3) * 16;
  *(s16x8*)(Wt + (size_t)(n0 + nr) * K + k0 + kc) = *(const s16x8*)&T[nr][kc];
  *(s16x8*)(Wt + (size_t)(n0 + nr) * K + k0 + kc + 8) =
      *(const s16x8*)&T[nr][kc + 8];
}

__global__ __launch_bounds__(256) void tconv_all(
    const float* __restrict__ wq, const float* __restrict__ wk,
    const float* __restrict__ wv, const float* __restrict__ wo,
    const float* __restrict__ w1, const float* __restrict__ w2,
    u16* __restrict__ qkvw, u16* __restrict__ wot, u16* __restrict__ w1t,
    u16* __restrict__ w2t) {
  const int idx = blockIdx.x, t = threadIdx.x;
  if (idx < 768) {
    const int which = idx >> 8, r = idx & 255;
    const float* W = which == 0 ? wq : (which == 1 ? wk : wv);
    tconv_tile(W, qkvw + which * 1048576, 1024, 1024, r & 15, r >> 4, t);
  } else if (idx < 1024) {
    const int r = idx - 768;
    tconv_tile(wo, wot, 1024, 1024, r & 15, r >> 4, t);
  } else if (idx < 2048) {
    const int r = idx - 1024;
    tconv_tile(w1, w1t, 1024, 4096, r & 63, r >> 6, t);
  } else {
    const int r = idx - 2048;
    tconv_tile(w2, w2t, 4096, 1024, r & 15, r >> 4, t);
  }
}

// ---------------- LayerNorm: fp32 [rows,1024] -> bf16 [rows,1024] ----------
__global__ __launch_bounds__(256) void ln_kernel(
    const float* __restrict__ x, const float* __restrict__ g,
    const float* __restrict__ b, u16* __restrict__ out) {
  const int row = blockIdx.x;
  const int t = threadIdx.x;
  const float* xr = x + (size_t)row * 1024;
  float4 v = *(const float4*)(xr + t * 4);
  float s = v.x + v.y + v.z + v.w;
  float ss = v.x * v.x + v.y * v.y + v.z * v.z + v.w * v.w;
#pragma unroll
  for (int off = 1; off < 64; off <<= 1) {
    s += __shfl_xor(s, off);
    ss += __shfl_xor(ss, off);
  }
  __shared__ float sb[4], ssb[4];
  const int w = t >> 6;
  if ((t & 63) == 0) { sb[w] = s; ssb[w] = ss; }
  __syncthreads();
  s = sb[0] + sb[1] + sb[2] + sb[3];
  ss = ssb[0] + ssb[1] + ssb[2] + ssb[3];
  const float mean = s * (1.0f / 1024.0f);
  const float var = ss * (1.0f / 1024.0f) - mean * mean;
  const float rstd = rsqrtf(var + 1e-5f);
  const int c = t * 4;
  ushort4 o;
  o.x = f2bf(g[c + 0] * ((v.x - mean) * rstd) + b[c + 0]);
  o.y = f2bf(g[c + 1] * ((v.y - mean) * rstd) + b[c + 1]);
  o.z = f2bf(g[c + 2] * ((v.z - mean) * rstd) + b[c + 2]);
  o.w = f2bf(g[c + 3] * ((v.w - mean) * rstd) + b[c + 3]);
  *(ushort4*)(out + (size_t)row * 1024 + c) = o;
}

// ---- XOR swizzle (64B LDS rows, 16B slots): phys_slot = log_slot ^ sw(row),
// sw(row) = (row>>1)&3. Write side pre-swizzles the GLOBAL source col since
// global_load_lds writes linearly.
// ---------------- GEMM 128^2 -----------------------------------------------
DEV void gemm_stage(const u16* __restrict__ A, const u16* __restrict__ Bt,
                    int bm, int bn, int K, int kof, u16 (*Al)[32],
                    u16 (*Bl)[32], int w, int lane) {
  const int srow = lane >> 2;
  const int scol = ((lane & 3) ^ ((lane >> 3) & 3)) * 8;  // swizzled source
#pragma unroll
  for (int p = 0; p < 2; ++p) {
    const int r0 = (w * 2 + p) * 16;
    GLOAD_LDS16(A + (size_t)(bm + r0 + srow) * K + kof + scol, &Al[r0][0]);
    GLOAD_LDS16(Bt + (size_t)(bn + r0 + srow) * K + kof + scol, &Bl[r0][0]);
  }
}

DEV void gemm_step(const u16 (*Al)[32], const u16 (*Bl)[32],
                   f32x4 (&acc)[4][4], int wm, int wn, int lr, int lg) {
  const int cs = (lg ^ ((lr >> 1) & 3)) * 8;  // swizzled read col
  s16x8 af[4], bf[4];
#pragma unroll
  for (int i = 0; i < 4; ++i) {
    af[i] = *(const s16x8*)&Al[wm + i * 16 + lr][cs];
    bf[i] = *(const s16x8*)&Bl[wn + i * 16 + lr][cs];
  }
#pragma unroll
  for (int i = 0; i < 4; ++i)
#pragma unroll
    for (int j = 0; j < 4; ++j)
      acc[i][j] = MFMA16(af[i], bf[j], acc[i][j], 0, 0, 0);
}

template <int EPI>
__global__ __launch_bounds__(256) void gemm_kernel(
    const u16* __restrict__ A, const u16* __restrict__ Bt,
    const float* __restrict__ bias, const float* __restrict__ res,
    void* __restrict__ Cv, int M, int N, int K) {
  __shared__ __align__(16) u16 Al[2][128][32];
  __shared__ __align__(16) u16 Bl[2][128][32];
  const int t = threadIdx.x;
  const int lane = t & 63, w = t >> 6;
  const int wm = (w >> 1) * 64, wn = (w & 1) * 64;
  int bid = blockIdx.y * gridDim.x + blockIdx.x;
  const int q8 = (gridDim.x * gridDim.y) >> 3;
  bid = (bid & 7) * q8 + (bid >> 3);
  const int bm = (bid / gridDim.x) * 128, bn = (bid % gridDim.x) * 128;
  const int lr = lane & 15, lg = lane >> 4;
  f32x4 acc[4][4] = {};
  const int nkt = K >> 5;

  gemm_stage(A, Bt, bm, bn, K, 0, Al[0], Bl[0], w, lane);
  __syncthreads();
  for (int kt = 0; kt < nkt - 1; ++kt) {
    const int cur = kt & 1;
    gemm_stage(A, Bt, bm, bn, K, (kt + 1) << 5, Al[cur ^ 1], Bl[cur ^ 1], w,
               lane);
    gemm_step(Al[cur], Bl[cur], acc, wm, wn, lr, lg);
    __syncthreads();
  }
  gemm_step(Al[(nkt - 1) & 1], Bl[(nkt - 1) & 1], acc, wm, wn, lr, lg);

#pragma unroll
  for (int i = 0; i < 4; ++i) {
    const int row = bm + wm + i * 16 + lg * 4;  // + e
#pragma unroll
    for (int j = 0; j < 4; ++j) {
      const int col = bn + wn + j * 16 + lr;
      if (EPI == 0) {
        const int bb = row >> 11, sloc = row & 2047;
        const int which = col >> 10, n = col & 1023;
        const int hh = n >> 6, dd = n & 63;
        u16* qbuf = (u16*)Cv;
        if (which == 2) {  // V transposed [bh][64][2048]
          ushort4 o;
          o.x = f2bf(acc[i][j][0]); o.y = f2bf(acc[i][j][1]);
          o.z = f2bf(acc[i][j][2]); o.w = f2bf(acc[i][j][3]);
          *(ushort4*)(qbuf + 8388608 +
                      (size_t)((bb * 16 + hh) * 64 + dd) * 2048 + sloc) = o;
        } else {
          // q pre-scaled by (1/8)*log2(e) so attention runs in exp2 space
          const float sc = (which == 0) ? 0.18033688011112042f : 1.0f;
          u16* dst = qbuf + (size_t)which * 4194304 +
                     ((size_t)(bb * 16 + hh) * 2048 + sloc) * 64 + dd;
#pragma unroll
          for (int e = 0; e < 4; ++e) dst[(size_t)e * 64] = f2bf(acc[i][j][e] * sc);
        }
      } else if (EPI == 1) {
        float* C = (float*)Cv;
        const float bs = bias[col];
#pragma unroll
        for (int e = 0; e < 4; ++e)
          C[(size_t)(row + e) * N + col] =
              acc[i][j][e] + bs + res[(size_t)(row + e) * N + col];
      } else {
        u16* C = (u16*)Cv;
        const float bs = bias[col];
#pragma unroll
        for (int e = 0; e < 4; ++e)
          C[(size_t)(row + e) * N + col] = f2bf(gelu_tanh(acc[i][j][e] + bs));
      }
    }
  }
}

// ---------------- GEMM 64^2: 4 waves, wave-tile 32x32, 4 blocks/CU ---------
DEV void g64_stage(const u16* __restrict__ A, const u16* __restrict__ Bt,
                   int bm, int bn, int K, int kof, u16 (*Al)[32],
                   u16 (*Bl)[32], int w, int lane) {
  const int srow = lane >> 2;
  const int scol = ((lane & 3) ^ ((lane >> 3) & 3)) * 8;
  const int r0 = w << 4;
  GLOAD_LDS16(A + (size_t)(bm + r0 + srow) * K + kof + scol, &Al[r0][0]);
  GLOAD_LDS16(Bt + (size_t)(bn + r0 + srow) * K + kof + scol, &Bl[r0][0]);
}

DEV void g64_step(const u16 (*Al)[32], const u16 (*Bl)[32],
                  f32x4 (&acc)[2][2], int wm, int wn, int lr, int lg) {
  const int cs = (lg ^ ((lr >> 1) & 3)) * 8;
  s16x8 af[2], bf[2];
#pragma unroll
  for (int i = 0; i < 2; ++i) {
    af[i] = *(const s16x8*)&Al[wm + i * 16 + lr][cs];
    bf[i] = *(const s16x8*)&Bl[wn + i * 16 + lr][cs];
  }
#pragma unroll
  for (int i = 0; i < 2; ++i)
#pragma unroll
    for (int j = 0; j < 2; ++j)
      acc[i][j] = MFMA16(af[i], bf[j], acc[i][j], 0, 0, 0);
}

template <int EPI>
__global__ __launch_bounds__(256) void gemm64_kernel(
    const u16* __restrict__ A, const u16* __restrict__ Bt,
    const float* __restrict__ bias, const float* __restrict__ res,
    void* __restrict__ Cv, int M, int N, int K) {
  __shared__ __align__(16) u16 Al[2][64][32];
  __shared__ __align__(16) u16 Bl[2][64][32];
  const int t = threadIdx.x;
  const int lane = t & 63, w = t >> 6;
  const int wm = (w >> 1) * 32, wn = (w & 1) * 32;
  int bid = blockIdx.y * gridDim.x + blockIdx.x;
  const int q8 = (gridDim.x * gridDim.y) >> 3;
  bid = (bid & 7) * q8 + (bid >> 3);
  const int bm = (bid / gridDim.x) * 64, bn = (bid % gridDim.x) * 64;
  const int lr = lane & 15, lg = lane >> 4;
  f32x4 acc[2][2] = {};
  const int nkt = K >> 5;

  g64_stage(A, Bt, bm, bn, K, 0, Al[0], Bl[0], w, lane);
  __syncthreads();
  for (int kt = 0; kt < nkt - 1; ++kt) {
    const int cur = kt & 1;
    g64_stage(A, Bt, bm, bn, K, (kt + 1) << 5, Al[cur ^ 1], Bl[cur ^ 1], w,
              lane);
    g64_step(Al[cur], Bl[cur], acc, wm, wn, lr, lg);
    __syncthreads();
  }
  g64_step(Al[(nkt - 1) & 1], Bl[(nkt - 1) & 1], acc, wm, wn, lr, lg);

#pragma unroll
  for (int i = 0; i < 2; ++i) {
    const int row = bm + wm + i * 16 + lg * 4;  // + e
#pragma unroll
    for (int j = 0; j < 2; ++j) {
      const int col = bn + wn + j * 16 + lr;
      if (EPI == 1) {
        float* C = (float*)Cv;
        const float bs = bias[col];
#pragma unroll
        for (int e = 0; e < 4; ++e)
          C[(size_t)(row + e) * N + col] =
              acc[i][j][e] + bs + res[(size_t)(row + e) * N + col];
      } else {
        u16* C = (u16*)Cv;
        const float bs = bias[col];
#pragma unroll
        for (int e = 0; e < 4; ++e)
          C[(size_t)(row + e) * N + col] = f2bf(gelu_tanh(acc[i][j][e] + bs));
      }
    }
  }
}

// ---------------- GEMM 256^2: 8 waves, wave-tile 128x64, BK=32 -------------
DEV void g256_stage(const u16* __restrict__ A, const u16* __restrict__ Bt,
                    int bm, int bn, int K, int kof, u16 (*Al)[32],
                    u16 (*Bl)[32], int w, int lane) {
  const int srow = lane >> 2;
  const int scol = ((lane & 3) ^ ((lane >> 3) & 3)) * 8;
#pragma unroll
  for (int c = 0; c < 2; ++c) {
    const int r0 = (w << 5) + (c << 4);
    GLOAD_LDS16(A + (size_t)(bm + r0 + srow) * K + kof + scol, &Al[r0][0]);
    GLOAD_LDS16(Bt + (size_t)(bn + r0 + srow) * K + kof + scol, &Bl[r0][0]);
  }
}

DEV void g256_step(const u16 (*Al)[32], const u16 (*Bl)[32],
                   f32x4 (&acc)[8][4], int wm, int wn, int lr, int lg) {
  const int cs = (lg ^ ((lr >> 1) & 3)) * 8;
  s16x8 af[8], bf[4];
#pragma unroll
  for (int i = 0; i < 8; ++i)
    af[i] = *(const s16x8*)&Al[wm + i * 16 + lr][cs];
#pragma unroll
  for (int j = 0; j < 4; ++j)
    bf[j] = *(const s16x8*)&Bl[wn + j * 16 + lr][cs];
#pragma unroll
  for (int i = 0; i < 8; ++i)
#pragma unroll
    for (int j = 0; j < 4; ++j)
      acc[i][j] = MFMA16(af[i], bf[j], acc[i][j], 0, 0, 0);
}

template <int EPI>
__global__ __launch_bounds__(512, 2) void gemm256_kernel(
    const u16* __restrict__ A, const u16* __restrict__ Bt,
    const float* __restrict__ bias, const float* __restrict__ res,
    void* __restrict__ Cv, int M, int N, int K) {
  __shared__ __align__(16) u16 Al[2][256][32];
  __shared__ __align__(16) u16 Bl[2][256][32];
  const int t = threadIdx.x;
  const int lane = t & 63, w = t >> 6;           // 8 waves
  const int wm = (w >> 2) << 7;                  // 0 / 128
  const int wn = (w & 3) << 6;                   // 0/64/128/192
  int bid = blockIdx.y * gridDim.x + blockIdx.x;
  const int q8 = (gridDim.x * gridDim.y) >> 3;
  bid = (bid & 7) * q8 + (bid >> 3);
  const int bm = (bid / gridDim.x) << 8, bn = (bid % gridDim.x) << 8;
  const int lr = lane & 15, lg = lane >> 4;
  f32x4 acc[8][4] = {};
  const int nkt = K >> 5;

  g256_stage(A, Bt, bm, bn, K, 0, Al[0], Bl[0], w, lane);
  __syncthreads();
  for (int kt = 0; kt < nkt - 1; ++kt) {
    const int cur = kt & 1;
    g256_stage(A, Bt, bm, bn, K, (kt + 1) << 5, Al[cur ^ 1], Bl[cur ^ 1], w,
               lane);
    g256_step(Al[cur], Bl[cur], acc, wm, wn, lr, lg);
    __syncthreads();
  }
  g256_step(Al[(nkt - 1) & 1], Bl[(nkt - 1) & 1], acc, wm, wn, lr, lg);

#pragma unroll
  for (int i = 0; i < 8; ++i) {
    const int row = bm + wm + i * 16 + lg * 4;  // + e
#pragma unroll
    for (int j = 0; j < 4; ++j) {
      const int col = bn + wn + j * 16 + lr;
      if (EPI == 1) {
        float* C = (float*)Cv;
        const float bs = bias[col];
#pragma unroll
        for (int e = 0; e < 4; ++e)
          C[(size_t)(row + e) * N + col] =
              acc[i][j][e] + bs + res[(size_t)(row + e) * N + col];
      } else {
        u16* C = (u16*)Cv;
        const float bs = bias[col];
#pragma unroll
        for (int e = 0; e < 4; ++e)
          C[(size_t)(row + e) * N + col] = f2bf(gelu_tanh(acc[i][j][e] + bs));
      }
    }
  }
}

// ---------------- Flash attention: 32x32 swapped, split-K dual-chain -------
DEV float vmax16(const f32x16& v) {
  float a = fmaxf(v[0], v[1]), b = fmaxf(v[2], v[3]);
  float c = fmaxf(v[4], v[5]), d = fmaxf(v[6], v[7]);
  float e = fmaxf(v[8], v[9]), f = fmaxf(v[10], v[11]);
  float g = fmaxf(v[12], v[13]), h = fmaxf(v[14], v[15]);
  a = fmaxf(a, b); c = fmaxf(c, d); e = fmaxf(e, f); g = fmaxf(g, h);
  return fmaxf(fmaxf(a, c), fmaxf(e, g));
}
DEV float vsum16(const f32x16& v) {
  float a = v[0] + v[1], b = v[2] + v[3];
  float c = v[4] + v[5], d = v[6] + v[7];
  float e = v[8] + v[9], f = v[10] + v[11];
  float g = v[12] + v[13], h = v[14] + v[15];
  a += b; c += d; e += f; g += h;
  return (a + c) + (e + g);
}

struct A32 {
  s16x8 q[4];
  f32x16 o0, o1;
  float m, l;
};

template <int MODE>  // 0 interior, 1 full-diag, 2 half-tile
DEV void body32(A32& st, int k0, const u16* Kb, const u16* Vb, int la,
                int hi) {
  s16x8 ka0[4], ka1[4];
#pragma unroll
  for (int c = 0; c < 4; ++c)
    ka0[c] = ld8(Kb + (size_t)(k0 + la) * 64 + c * 16 + hi * 8);
  if (MODE != 2)
#pragma unroll
    for (int c = 0; c < 4; ++c)
      ka1[c] = ld8(Kb + (size_t)(k0 + 32 + la) * 64 + c * 16 + hi * 8);
  f32x16 s0, s1;
#pragma unroll
  for (int r = 0; r < 16; ++r) { s0[r] = 0.f; s1[r] = 0.f; }
#pragma unroll
  for (int c = 0; c < 4; ++c) s0 = MFMA32(ka0[c], st.q[c], s0, 0, 0, 0);
  if (MODE != 2)
#pragma unroll
    for (int c = 0; c < 4; ++c) s1 = MFMA32(ka1[c], st.q[c], s1, 0, 0, 0);
  const int nkc = (MODE == 2) ? 2 : 4;
  s16x8 va0[4], va1[4];
#pragma unroll
  for (int kc = 0; kc < 4; ++kc)
    if (kc < nkc) {
      va0[kc] = ld8(Vb + (size_t)la * 2048 + k0 + kc * 16 + hi * 8);
      va1[kc] = ld8(Vb + (size_t)(32 + la) * 2048 + k0 + kc * 16 + hi * 8);
    }
  if (MODE == 1) {
#pragma unroll
    for (int r = 0; r < 16; ++r) {
      const int kl = (r & 3) + 8 * (r >> 2) + 4 * hi;
      if (kl > la) s1[r] = -INFINITY;
    }
  }
  if (MODE == 2) {
#pragma unroll
    for (int r = 0; r < 16; ++r) {
      const int kl = (r & 3) + 8 * (r >> 2) + 4 * hi;
      if (kl > la) s0[r] = -INFINITY;
    }
  }
  float mt = vmax16(s0);
  if (MODE != 2) mt = fmaxf(mt, vmax16(s1));
  mt = fmaxf(mt, __shfl_xor(mt, 32));
  // defer-max (T13): skip rescale when max growth <= 8 (exp2 space)
  const bool skip = __all(mt <= st.m + 8.0f) != 0;
  const float mn = skip ? st.m : fmaxf(st.m, mt);
  const float sf = skip ? 1.0f : exp2f(st.m - mn);
#pragma unroll
  for (int r = 0; r < 16; ++r) s0[r] = exp2f(s0[r] - mn);
  if (MODE != 2)
#pragma unroll
    for (int r = 0; r < 16; ++r) s1[r] = exp2f(s1[r] - mn);
  float rs = vsum16(s0);
  if (MODE != 2) rs += vsum16(s1);
  rs += __shfl_xor(rs, 32);
  st.l = skip ? (st.l + rs) : (st.l * sf + rs);
  st.m = mn;
  if (!skip) {
#pragma unroll
    for (int r = 0; r < 16; ++r) { st.o0[r] *= sf; st.o1[r] *= sf; }
  }
  const int nh = (MODE == 2) ? 1 : 2;
#pragma unroll
  for (int half = 0; half < nh; ++half) {
    u32 w[8];
#pragma unroll
    for (int i = 0; i < 8; ++i)
      w[i] = half ? cvtpk(s1[2 * i], s1[2 * i + 1])
                  : cvtpk(s0[2 * i], s0[2 * i + 1]);
#pragma unroll
    for (int kp = 0; kp < 2; ++kp) {
      const u32 w0 = w[4 * kp + 0], w1 = w[4 * kp + 1];
      const u32 w2 = w[4 * kp + 2], w3 = w[4 * kp + 3];
      const u32 t0 = hi ? w0 : w2, t1 = hi ? w1 : w3;
      const u32 x0 = (u32)__shfl_xor((int)t0, 32);
      const u32 x1 = (u32)__shfl_xor((int)t1, 32);
      union { u32 u[4]; s16x8 v; } bb;
      bb.u[0] = hi ? x0 : w0;
      bb.u[1] = hi ? x1 : w1;
      bb.u[2] = hi ? w2 : x0;
      bb.u[3] = hi ? w3 : x1;
      const int kc = half * 2 + kp;
      st.o0 = MFMA32(va0[kc], bb.v, st.o0, 0, 0, 0);
      st.o1 = MFMA32(va1[kc], bb.v, st.o1, 0, 0, 0);
    }
  }
}

DEV void a32_init(A32& st, const u16* Qbase, int qs, int la, int hi) {
#pragma unroll
  for (int c = 0; c < 4; ++c)
    st.q[c] = ld8(Qbase + (size_t)(qs + la) * 64 + c * 16 + hi * 8);
#pragma unroll
  for (int r = 0; r < 16; ++r) { st.o0[r] = 0.f; st.o1[r] = 0.f; }
  st.m = -INFINITY;
  st.l = 0.f;
}

// emit unnormalized partial: O bf16 [32 rows][64 cols], m/l fp32 [32]+[32]
DEV void a32_emit(const A32& st, u16* __restrict__ pO, float* __restrict__ pml,
                  int p, int la, int hi) {
  u16* po = pO + (size_t)p * 2048 + la * 64;
#pragma unroll
  for (int r = 0; r < 16; r += 2) {
    const int d = (r & 3) + 8 * (r >> 2) + 4 * hi;
    *(u32*)(po + d) = cvtpk(st.o0[r], st.o0[r + 1]);
    *(u32*)(po + 32 + d) = cvtpk(st.o1[r], st.o1[r + 1]);
  }
  if (hi == 0) {
    pml[p * 64 + la] = st.m;
    pml[p * 64 + 32 + la] = st.l;
  }
}

// tail body for chunk t at k-tile nf = t>>1 (mode1 odd / mode2 even)
DEV void body_tail(A32& st, int t, const u16* Kb, const u16* Vb, int la,
                   int hi) {
  const int nf = t >> 1;
  if (t & 1) body32<1>(st, nf * 64, Kb, Vb, la, hi);
  else       body32<2>(st, nf * 64, Kb, Vb, la, hi);
}

// blockIdx.x = tA*2 + h: pair (tA, 63-tA), key-half h. All waves ~equal work.
__global__ __launch_bounds__(64) void attn_kernel(
    const u16* __restrict__ Qg, const u16* __restrict__ Kg,
    const u16* __restrict__ Vt, u16* __restrict__ pO,
    float* __restrict__ pml) {
  const int lane = threadIdx.x & 63;
  const int la = lane & 31, hi = lane >> 5;
  const int tA = blockIdx.x >> 1, h = blockIdx.x & 1;
  const int bh = blockIdx.y;
  const int tB = 63 - tA;
  const int qsA = tA * 32, qsB = tB * 32;
  const int nA = (tA >> 1) + 1, nB = (tB >> 1) + 1;  // bodies incl tail
  const int cA = (nA + 1) >> 1, cB = (nB + 1) >> 1;  // half split (ceil)
  const int a0 = h ? cA : 0, a1 = h ? nA : cA;
  const int b0 = h ? cB : 0, b1 = h ? nB : cB;
  const int aiEnd = min(a1, nA - 1), biEnd = min(b1, nB - 1);
  const bool aTail = (a1 == nA) && (a1 > a0);
  const bool bTail = (b1 == nB) && (b1 > b0);
  const size_t baseK = (size_t)bh * 2048 * 64;
  const size_t baseV = (size_t)bh * 64 * 2048;
  const u16* Kb = Kg + baseK;
  const u16* Vb = Vt + baseV;

  A32 A, B;
  a32_init(A, Qg + baseK, qsA, la, hi);
  a32_init(B, Qg + baseK, qsB, la, hi);

  int ia = a0, ib = b0;
  const int common = min(aiEnd - a0, biEnd - b0);
  for (int i = 0; i < common; ++i) {       // lockstep interiors (ILP=2)
    body32<0>(B, ib * 64, Kb, Vb, la, hi); ++ib;
    body32<0>(A, ia * 64, Kb, Vb, la, hi); ++ia;
  }
  for (; ib < biEnd; ++ib) body32<0>(B, ib * 64, Kb, Vb, la, hi);
  for (; ia < aiEnd; ++ia) body32<0>(A, ia * 64, Kb, Vb, la, hi);
  if (bTail) body_tail(B, tB, Kb, Vb, la, hi);
  if (aTail) body_tail(A, tA, Kb, Vb, la, hi);

  const int pA = (((bh << 6) | tA) << 1) | h;
  const int pB = (((bh << 6) | tB) << 1) | h;
  a32_emit(A, pO, pml, pA, la, hi);
  a32_emit(B, pO, pml, pB, la, hi);
}

// ---------------- combine two key-half partials -> ctx bf16 ----------------
__global__ __launch_bounds__(64) void attn_combine(
    const u16* __restrict__ pO, const float* __restrict__ pml,
    u16* __restrict__ ctx) {
  const int t = blockIdx.x, bh = blockIdx.y;   // grid (64, 32)
  const int lane = threadIdx.x & 63;
  const int la = lane & 31, hi = lane >> 5;
  const int p0 = ((bh << 6) | t) << 1;
  const float m0 = pml[p0 * 64 + la], l0 = pml[p0 * 64 + 32 + la];
  const float m1 = pml[(p0 + 1) * 64 + la], l1 = pml[(p0 + 1) * 64 + 32 + la];
  const float M = fmaxf(m0, m1);
  const float w0 = exp2f(m0 - M), w1 = exp2f(m1 - M);
  const float inv = 1.0f / (l0 * w0 + l1 * w1);
  const float f0 = w0 * inv, f1 = w1 * inv;
  const u16* o0 = pO + (size_t)p0 * 2048 + la * 64 + hi * 32;
  const u16* o1 = o0 + 2048;
  const int bb = bh >> 4, hh = bh & 15;
  u16* crow = ctx + (size_t)(bb * 2048 + t * 32 + la) * 1024 + hh * 64 +
              hi * 32;
#pragma unroll
  for (int j = 0; j < 32; j += 8) {
    s16x8 a = ld8(o0 + j), b = ld8(o1 + j);
    union { u32 u[4]; s16x8 v; } o;
#pragma unroll
    for (int i = 0; i < 4; ++i) {
      const float e0 = bf2f((u16)a[2 * i]) * f0 + bf2f((u16)b[2 * i]) * f1;
      const float e1 =
          bf2f((u16)a[2 * i + 1]) * f0 + bf2f((u16)b[2 * i + 1]) * f1;
      o.u[i] = cvtpk(e0, e1);
    }
    *(s16x8*)(crow + j) = o.v;
  }
}

// ---------------------------------------------------------------------------
extern "C" void kernel_launch(void* const* d_in, const int* in_sizes, int n_in,
                              void* d_out, int out_size, void* d_ws,
                              size_t ws_size, hipStream_t stream) {
  const float* x  = (const float*)d_in[0];
  const float* wq = (const float*)d_in[1];
  const float* wk = (const float*)d_in[2];
  const float* wv = (const float*)d_in[3];
  const float* wo = (const float*)d_in[4];
  const float* bo = (const float*)d_in[5];
  const float* w1 = (const float*)d_in[6];
  const float* b1 = (const float*)d_in[7];
  const float* w2 = (const float*)d_in[8];
  const float* b2 = (const float*)d_in[9];
  const float* g1 = (const float*)d_in[10];
  const float* s1 = (const float*)d_in[11];
  const float* g2 = (const float*)d_in[12];
  const float* s2 = (const float*)d_in[13];
  float* out = (float*)d_out;

  // ws (MB): 0-8 hb | 8-32 qbuf | 32-40 ctxb | 40-56 pO (attn->combine) then
  // x2 (proj onward) | 56-57 pml | 57-65 h2b | 65-71 qkvw | 71-73 wot |
  // 73-81 w1t | 81-89 w2t | gb aliases 0-32 during FFN.
  const size_t MB = (size_t)1 << 20;
  char* p = (char*)d_ws;
  u16* hb    = (u16*)(p + 0 * MB);
  u16* qbuf  = (u16*)(p + 8 * MB);
  u16* ctxb  = (u16*)(p + 32 * MB);
  u16* pO    = (u16*)(p + 40 * MB);
  float* x2  = (float*)(p + 40 * MB);
  float* pml = (float*)(p + 56 * MB);
  u16* h2b   = (u16*)(p + 57 * MB);
  u16* qkvw  = (u16*)(p + 65 * MB);
  u16* wot   = (u16*)(p + 71 * MB);
  u16* w1t   = (u16*)(p + 73 * MB);
  u16* w2t   = (u16*)(p + 81 * MB);
  u16* gb    = (u16*)(p + 0 * MB);

  const dim3 blk(256);
  tconv_all<<<dim3(3072), blk, 0, stream>>>(wq, wk, wv, wo, w1, w2, qkvw, wot,
                                            w1t, w2t);
  ln_kernel<<<4096, blk, 0, stream>>>(x, g1, s1, hb);
  gemm_kernel<0><<<dim3(24, 32), blk, 0, stream>>>(hb, qkvw, nullptr, nullptr,
                                                   qbuf, 4096, 3072, 1024);
  attn_kernel<<<dim3(64, 32), dim3(64), 0, stream>>>(
      qbuf, qbuf + 4194304, qbuf + 8388608, pO, pml);
  attn_combine<<<dim3(64, 32), dim3(64), 0, stream>>>(pO, pml, ctxb);
  gemm64_kernel<1><<<dim3(16, 64), blk, 0, stream>>>(ctxb, wot, bo, x, x2,
                                                     4096, 1024, 1024);
  ln_kernel<<<4096, blk, 0, stream>>>(x2, g2, s2, h2b);
  gemm256_kernel<2><<<dim3(16, 16), dim3(512), 0, stream>>>(
      h2b, w1t, b1, nullptr, gb, 4096, 4096, 1024);
  gemm64_kernel<1><<<dim3(16, 64), blk, 0, stream>>>(gb, w2t, b2, x2, out,
                                                     4096, 1024, 4096);
}